// Round 8
// baseline (533.065 us; speedup 1.0000x reference)
//
#include <hip/hip_runtime.h>
#include <hip/hip_cooperative_groups.h>
#include <stdint.h>
#include <math.h>

namespace cg = cooperative_groups;

#define DMODEL 1280
#define NHEAD  20
#define DHEAD  64
#define NSEG   4
#define MAXS   1500
#define SPAD   1536              // padded per-segment kv length (multiple of 64)
#define TPAD   (NSEG*SPAD)       // 6144
#define BM 128
#define BN 128
#define BK 32
#define NJ_QKV (30*47)           // 1410 qkv tile-jobs
#define NJ_ATTN (NSEG*NHEAD*12)  // 960 attn jobs (4-wave, 128 q-rows)
#define NJ_OUT (10*47)           // 470 out-proj tile-jobs
#define QSCALE 0.18033688011112042f  // 0.125 * log2(e): fold softmax scale+log2e into Q
#define NEGV  -1e30f

typedef float  f32x4  __attribute__((ext_vector_type(4)));
typedef __bf16 bf16x8 __attribute__((ext_vector_type(8)));

#if __has_builtin(__builtin_amdgcn_exp2f)
#define EXP2F(x) __builtin_amdgcn_exp2f(x)
#else
#define EXP2F(x) exp2f(x)
#endif

__device__ __forceinline__ ushort f2bf(float f) {
  union { float f; uint32_t u; } a; a.f = f;
  uint32_t u = a.u;
  u += 0x7FFFu + ((u >> 16) & 1u);   // RNE
  return (ushort)(u >> 16);
}

// async global->LDS, 16B per lane: lane i lands at lds + i*16 (wave-uniform base).
__device__ __forceinline__ void async16(const void* g, void* lds) {
  __builtin_amdgcn_global_load_lds((const __attribute__((address_space(1))) void*)g,
                                   (__attribute__((address_space(3))) void*)lds,
                                   16, 0, 0);
}

// kv permutation within each 32-block of the transposed-V layout:
// stored position p <-> actual offset a, p = ((a>>2)&3)*8 + ((a>>4)&1)*4 + (a&3)
__device__ __forceinline__ int perm32(int a) {
  return ((a >> 2) & 3) * 8 + ((a >> 4) & 1) * 4 + (a & 3);
}

// ---------------- phase bodies (shared by mega kernel and fallback kernels) ----------------

// fp32 -> bf16 convert: X then 4 weights (contiguous dst); grid-stride (proven R6 body)
__device__ __forceinline__ void cvt_phase(
    const float* __restrict__ hs, const float* __restrict__ Wq,
    const float* __restrict__ Wk, const float* __restrict__ Wv,
    const float* __restrict__ Wo, ushort* __restrict__ dst, int nX, int DD)
{
  const int ng = (nX + 4 * DD) >> 3;
  const int stride = gridDim.x * 256;
  for (int g = blockIdx.x * 256 + threadIdx.x; g < ng; g += stride) {
    const int i = g << 3;
    const float* src;
    if (i < nX) {
      src = hs + i;
    } else {
      const int j = i - nX;
      const int z = (j >= DD) + (j >= 2 * DD) + (j >= 3 * DD);
      const float* w = (z == 0) ? Wq : (z == 1) ? Wk : (z == 2) ? Wv : Wo;
      src = w + (j - z * DD);
    }
    const float4 v0 = ((const float4*)src)[0];
    const float4 v1 = ((const float4*)src)[1];
    ushort4 o0, o1;
    o0.x = f2bf(v0.x); o0.y = f2bf(v0.y); o0.z = f2bf(v0.z); o0.w = f2bf(v0.w);
    o1.x = f2bf(v1.x); o1.y = f2bf(v1.y); o1.z = f2bf(v1.z); o1.w = f2bf(v1.w);
    ((ushort4*)(dst + i))[0] = o0;
    ((ushort4*)(dst + i))[1] = o1;
  }
}

// 128x128 GEMM mainloop (C = A[M,K] * W[N,K]^T) — R2-proven: 2-buffer global_load_lds,
// 64 super-rows x 8 16B chunks, chunk pos p' = p ^ (sr&7); measured 0 bank conflicts.
__device__ __forceinline__ void gemm_tile_mainloop(
    const ushort* __restrict__ A, const ushort* __restrict__ W,
    int M, int m0, int n0, ushort* As, ushort* Bs, f32x4 (&acc)[4][4])
{
  const int tid  = threadIdx.x;
  const int wave = tid >> 6, lane = tid & 63;
  const int quad = lane >> 4, c16 = lane & 15;
  const int wr = (wave >> 1) * 64, wc = (wave & 1) * 64;

  const int M0 = wave * 128 + lane, M1 = M0 + 64;
  const int sr0 = M0 >> 3, pp0 = M0 & 7, p0 = pp0 ^ (sr0 & 7);
  const int sr1 = M1 >> 3, pp1 = M1 & 7, p1 = pp1 ^ (sr1 & 7);
  const int row0 = sr0 * 2 + (p0 >> 2), kc0 = (p0 & 3) << 3;
  const int row1 = sr1 * 2 + (p1 >> 2), kc1 = (p1 & 3) << 3;
  // no row clamp: OOB rows (m-edge tile) read into the next ws region; results masked at store
  const ushort* Ap0 = A + (size_t)(m0 + row0) * DMODEL + kc0;
  const ushort* Ap1 = A + (size_t)(m0 + row1) * DMODEL + kc1;
  const ushort* Bp0 = W + (size_t)(n0 + row0) * DMODEL + kc0;
  const ushort* Bp1 = W + (size_t)(n0 + row1) * DMODEL + kc1;
  const int o0 = wave * 1024;
  const int o1 = wave * 1024 + 512;
  const int BUF = BM * BK;           // 4096 ushorts per buffer

  async16(Ap0, As + o0); async16(Ap1, As + o1);
  async16(Bp0, Bs + o0); async16(Bp1, Bs + o1);

  int c = 0;
  for (int k0 = 0; k0 < DMODEL; k0 += BK, c ^= 1) {
    __syncthreads();                 // publishes buf c (drains the staging loads)
    if (k0 + BK < DMODEL) {
      const int kn = k0 + BK;
      const int bo = (c ^ 1) * BUF;
      async16(Ap0 + kn, As + bo + o0); async16(Ap1 + kn, As + bo + o1);
      async16(Bp0 + kn, Bs + bo + o0); async16(Bp1 + kn, Bs + bo + o1);
    }
    const ushort* Ab = As + c * BUF;
    const ushort* Bb = Bs + c * BUF;
    bf16x8 a[4], b[4];
#pragma unroll
    for (int i = 0; i < 4; ++i) {
      const int row = wr + i * 16 + c16;
      const int sr = row >> 1;
      const int off = (sr << 6) + (((((row & 1) << 2) | quad) ^ (sr & 7)) << 3);
      a[i] = *(const bf16x8*)(Ab + off);
    }
#pragma unroll
    for (int j = 0; j < 4; ++j) {
      const int row = wc + j * 16 + c16;
      const int sr = row >> 1;
      const int off = (sr << 6) + (((((row & 1) << 2) | quad) ^ (sr & 7)) << 3);
      b[j] = *(const bf16x8*)(Bb + off);
    }
#pragma unroll
    for (int i = 0; i < 4; ++i)
#pragma unroll
      for (int j = 0; j < 4; ++j)
        acc[i][j] = __builtin_amdgcn_mfma_f32_16x16x32_bf16(a[i], b[j], acc[i][j], 0, 0, 0);
  }
}

// one qkv tile-job: job = wg*47 + mt, wg = z*10 + nn  (R6-proven epilogues)
__device__ __forceinline__ void qkv_job(
    int job, const ushort* __restrict__ X, const ushort* __restrict__ W4,
    const float* __restrict__ bq, const float* __restrict__ bv,
    const int* __restrict__ cu,
    ushort* __restrict__ qb, ushort* __restrict__ kb, ushort* __restrict__ vt,
    int M, ushort* As, ushort* Bs)
{
  const int wg = job / 47, mt = job - wg * 47;
  const int z = wg / 10;
  const int n0 = (wg - z * 10) * BN;
  const int m0 = mt * BM;
  const ushort* W = W4 + (size_t)z * DMODEL * DMODEL;

  f32x4 acc[4][4];
  f32x4 zero = {0.f, 0.f, 0.f, 0.f};
#pragma unroll
  for (int i = 0; i < 4; ++i)
#pragma unroll
    for (int j = 0; j < 4; ++j) acc[i][j] = zero;

  gemm_tile_mainloop(X, W, M, m0, n0, As, Bs, acc);

  const int tid = threadIdx.x, wave = tid >> 6, lane = tid & 63;
  const int quad = lane >> 4, c16 = lane & 15;
  const int wr = (wave >> 1) * 64, wc = (wave & 1) * 64;

  if (z == 2) {
    const int c1 = cu[1], c2 = cu[2], c3 = cu[3];
#pragma unroll
    for (int i = 0; i < 4; ++i) {
      const int t0 = m0 + wr + i * 16 + quad * 4;
      const int s0a = (t0 >= c1) + (t0 >= c2) + (t0 >= c3);
      const int s3a = (t0 + 3 >= c1) + (t0 + 3 >= c2) + (t0 + 3 >= c3);
      const int seg0 = (s0a == 0) ? 0 : (s0a == 1) ? c1 : (s0a == 2) ? c2 : c3;
#pragma unroll
      for (int j = 0; j < 4; ++j) {
        const int cfeat = n0 + wc + j * 16 + c16;
        const float bb = bv[cfeat];
        if (t0 + 3 < M && s0a == s3a) {
          const int s = t0 - seg0;                 // s ≡ t0 (mod 4): boundaries are mult of 4
          const size_t base = (size_t)cfeat * TPAD + (size_t)s0a * SPAD
                            + (size_t)(s & ~31) + perm32(s & 31);
          ushort4 w;
          w.x = f2bf(acc[i][j][0] + bb);
          w.y = f2bf(acc[i][j][1] + bb);
          w.z = f2bf(acc[i][j][2] + bb);
          w.w = f2bf(acc[i][j][3] + bb);
          *(ushort4*)(vt + base) = w;
        } else {
#pragma unroll
          for (int r = 0; r < 4; ++r) {
            const int t = t0 + r;
            if (t < M) {
              const int sb = (t >= c1) + (t >= c2) + (t >= c3);
              const int sg = (sb == 0) ? 0 : (sb == 1) ? c1 : (sb == 2) ? c2 : c3;
              const int s = t - sg;
              vt[(size_t)cfeat * TPAD + (size_t)sb * SPAD + (s & ~31) + perm32(s & 31)]
                  = f2bf(acc[i][j][r] + bb);
            }
          }
        }
      }
    }
  } else {
    ushort* out = (z == 0) ? qb : kb;
    const float* bias = (z == 0) ? bq : (const float*)nullptr;
    const float oscale = (z == 0) ? QSCALE : 1.0f;
#pragma unroll
    for (int i = 0; i < 4; ++i) {
      const int rbase = m0 + wr + i * 16 + quad * 4;
#pragma unroll
      for (int j = 0; j < 4; ++j) {
        const int c = n0 + wc + j * 16 + c16;
        const float bb = bias ? bias[c] : 0.f;
#pragma unroll
        for (int r = 0; r < 4; ++r) {
          const int rr = rbase + r;
          if (rr < M) out[(size_t)rr * DMODEL + c] = f2bf((acc[i][j][r] + bb) * oscale);
        }
      }
    }
  }
}

// one attn job: 4-wave, 128 q-rows (round-0-proven body + cast P-packing + setprio).
// job = qt*80 + hs. SBf = 32 KB LDS: Q staged in SBf[0..8191], then [2][8192] kv dbuf.
__device__ __forceinline__ void attn_job(
    int job, const ushort* __restrict__ qb, const ushort* __restrict__ kb,
    const ushort* __restrict__ vt, ushort* __restrict__ ob,
    const int* __restrict__ cu, ushort* SBf)
{
  const int qt = job / 80, hs = job - qt * 80;
  const int b = hs / NHEAD, h = hs - b * NHEAD;
  const int seg0 = cu[b];
  const int len  = cu[b + 1] - seg0;
  const int q0 = qt * 128;                     // qt<12 -> q0<=1408 < len(=1500) always
  const int tid = threadIdx.x, wave = tid >> 6, lane = tid & 63;
  const int quad = lane >> 4, c16 = lane & 15;

  __syncthreads();   // job-loop safety: prior job's LDS reads complete before Q staging

  // ---- stage Q (128 rows x 64 d = 16KB) into SBf[0..8191], swizzled chunks ----
  {
    const int s = wave * 64 + lane;
#pragma unroll
    for (int t = 0; t < 4; ++t) {
      const int slot = t * 256 + s;
      const int r = slot >> 3, k2 = slot & 7;
      const int col = ((k2 ^ (r & 7)) << 3);
      async16(qb + (size_t)(seg0 + q0 + r) * DMODEL + h * DHEAD + col,
              &SBf[(t * 256 + wave * 64) * 8]);
    }
  }

  // ---- per-lane K/V staging pointers ----
  const int sl  = wave * 64 + lane;
  const int rr0 = sl >> 3, kk2 = sl & 7;
  const int colc = ((kk2 ^ (rr0 & 7)) << 3);
  const ushort* kp0 = kb + (size_t)(seg0 + rr0) * DMODEL + h * DHEAD + colc;
  const ushort* kp1 = kp0 + (size_t)32 * DMODEL;
  const ushort* vp0 = vt + (size_t)(h * DHEAD + rr0) * TPAD + (size_t)b * SPAD + colc;
  const ushort* vp1 = vp0 + (size_t)32 * TPAD;
  const int ldo0 = wave * 512;
  const int ldo1 = 2048 + wave * 512;

  __syncthreads();   // Q published

  bf16x8 aq[2][2];
#pragma unroll
  for (int n = 0; n < 2; ++n)
#pragma unroll
    for (int ks = 0; ks < 2; ++ks) {
      const int row = wave * 32 + n * 16 + c16;
      aq[n][ks] = *(const bf16x8*)(&SBf[row * 64 + (((ks * 4 + quad) ^ (c16 & 7)) << 3)]);
    }

  __syncthreads();   // Q reads done; SBf[0] reusable as kv buffer

  // stage kv tile 0 into SBf[1] region
  async16(kp0, &SBf[8192 + ldo0]);        async16(kp1, &SBf[8192 + ldo1]);
  async16(vp0, &SBf[8192 + 4096 + ldo0]); async16(vp1, &SBf[8192 + 4096 + ldo1]);
  kp0 += (size_t)64 * DMODEL; kp1 += (size_t)64 * DMODEL; vp0 += 64; vp1 += 64;

  float l_i[2] = {0.f, 0.f};
  f32x4 o_acc[2][4];
  f32x4 zero = {0.f, 0.f, 0.f, 0.f};
#pragma unroll
  for (int n = 0; n < 2; ++n)
#pragma unroll
    for (int m = 0; m < 4; ++m) o_acc[n][m] = zero;

  const int niter = (len + 63) >> 6;
  for (int it = 0; it < niter; ++it) {
    __syncthreads();
    const ushort* Kt = SBf + (1 ^ (it & 1)) * 8192;
    const ushort* Vt = Kt + 4096;

    if (it + 1 < niter) {
      ushort* Dst = SBf + (it & 1) * 8192;
      async16(kp0, Dst + ldo0);        async16(kp1, Dst + ldo1);
      async16(vp0, Dst + 4096 + ldo0); async16(vp1, Dst + 4096 + ldo1);
      kp0 += (size_t)64 * DMODEL; kp1 += (size_t)64 * DMODEL; vp0 += 64; vp1 += 64;
    }

    // S^T = K * Q^T
    f32x4 s[2][4];
    __builtin_amdgcn_s_setprio(1);
#pragma unroll
    for (int f = 0; f < 4; ++f) {
      const int row = f * 16 + c16;
      const int ch = c16 & 7;
      bf16x8 ak0 = *(const bf16x8*)(Kt + row * 64 + ((quad ^ ch) << 3));
      bf16x8 ak1 = *(const bf16x8*)(Kt + row * 64 + (((4 + quad) ^ ch) << 3));
#pragma unroll
      for (int n = 0; n < 2; ++n) {
        s[n][f] = zero;
        s[n][f] = __builtin_amdgcn_mfma_f32_16x16x32_bf16(ak0, aq[n][0], s[n][f], 0, 0, 0);
        s[n][f] = __builtin_amdgcn_mfma_f32_16x16x32_bf16(ak1, aq[n][1], s[n][f], 0, 0, 0);
      }
    }
    __builtin_amdgcn_s_setprio(0);

    const int kv0 = it * 64;
    if (kv0 + 64 > len) {
#pragma unroll
      for (int f = 0; f < 4; ++f) {
        const int kvb = kv0 + f * 16 + quad * 4;
#pragma unroll
        for (int r = 0; r < 4; ++r)
          if (kvb + r >= len) { s[0][f][r] = NEGV; s[1][f][r] = NEGV; }
      }
    }

#pragma unroll
    for (int n = 0; n < 2; ++n) {
      float rs = 0.f;
#pragma unroll
      for (int f = 0; f < 4; ++f)
#pragma unroll
        for (int r = 0; r < 4; ++r) {
          const float p = EXP2F(s[n][f][r]);
          s[n][f][r] = p;
          rs += p;
        }
      l_i[n] += rs;
    }

    // P -> bf16 via compiler casts (v_cvt_pk_bf16_f32; proven ~6us faster than bit-pack)
    bf16x8 bp[2][2];
#pragma unroll
    for (int n = 0; n < 2; ++n)
#pragma unroll
      for (int g = 0; g < 2; ++g) {
        bf16x8 t;
#pragma unroll
        for (int r = 0; r < 4; ++r) {
          t[r]     = (__bf16)s[n][2 * g][r];
          t[r + 4] = (__bf16)s[n][2 * g + 1][r];
        }
        bp[n][g] = t;
      }

    // O^T += V^T * P^T
    __builtin_amdgcn_s_setprio(1);
#pragma unroll
    for (int m = 0; m < 4; ++m) {
      const int row = m * 16 + c16;
      const int ch = c16 & 7;
      bf16x8 av0 = *(const bf16x8*)(Vt + row * 64 + ((quad ^ ch) << 3));
      bf16x8 av1 = *(const bf16x8*)(Vt + row * 64 + (((4 + quad) ^ ch) << 3));
#pragma unroll
      for (int n = 0; n < 2; ++n) {
        o_acc[n][m] = __builtin_amdgcn_mfma_f32_16x16x32_bf16(av0, bp[n][0], o_acc[n][m], 0, 0, 0);
        o_acc[n][m] = __builtin_amdgcn_mfma_f32_16x16x32_bf16(av1, bp[n][1], o_acc[n][m], 0, 0, 0);
      }
    }
    __builtin_amdgcn_s_setprio(0);
  }

  // epilogue
#pragma unroll
  for (int n = 0; n < 2; ++n) {
    float l = l_i[n];
    l += __shfl_xor(l, 16);
    l += __shfl_xor(l, 32);
    const int q = q0 + wave * 32 + n * 16 + c16;
    if (q < len) {
      const float inv = 1.0f / l;
      const size_t base = (size_t)(seg0 + q) * DMODEL + h * DHEAD;
#pragma unroll
      for (int m = 0; m < 4; ++m) {
        ushort4 pk;
        pk.x = f2bf(o_acc[n][m][0] * inv);
        pk.y = f2bf(o_acc[n][m][1] * inv);
        pk.z = f2bf(o_acc[n][m][2] * inv);
        pk.w = f2bf(o_acc[n][m][3] * inv);
        *(ushort4*)(ob + base + m * 16 + quad * 4) = pk;
      }
    }
  }
}

// one out-proj tile-job: job = nn*47 + mt (R2-proven body, fp32 out)
__device__ __forceinline__ void out_job(
    int job, const ushort* __restrict__ A, const ushort* __restrict__ W,
    const float* __restrict__ bias, float* __restrict__ out, int M,
    ushort* As, ushort* Bs)
{
  const int nn = job / 47, mt = job - nn * 47;
  const int n0 = nn * BN, m0 = mt * BM;
  f32x4 acc[4][4];
  f32x4 zero = {0.f, 0.f, 0.f, 0.f};
#pragma unroll
  for (int i = 0; i < 4; ++i)
#pragma unroll
    for (int j = 0; j < 4; ++j) acc[i][j] = zero;

  gemm_tile_mainloop(A, W, M, m0, n0, As, Bs, acc);

  const int tid = threadIdx.x, wave = tid >> 6, lane = tid & 63;
  const int quad = lane >> 4, c16 = lane & 15;
  const int wr = (wave >> 1) * 64, wc = (wave & 1) * 64;
#pragma unroll
  for (int i = 0; i < 4; ++i) {
    const int rbase = m0 + wr + i * 16 + quad * 4;
#pragma unroll
    for (int j = 0; j < 4; ++j) {
      const int c = n0 + wc + j * 16 + c16;
      const float bb = bias[c];
#pragma unroll
      for (int r = 0; r < 4; ++r) {
        const int rr = rbase + r;
        if (rr < M) out[(size_t)rr * DMODEL + c] = acc[i][j][r] + bb;
      }
    }
  }
}

// ---------------- mega kernel: all phases, one dispatch, grid.sync between ----------------
struct MegaArgs {
  const float *hs, *Wq, *Wk, *Wv, *Wo, *bq, *bv, *bo;
  const int* cu;
  float* out;
  ushort *X, *W4, *qb, *kb, *vt;    // ob aliases X
  int T, nX, DD;
};

__global__ void __launch_bounds__(256, 4)
mega(MegaArgs a)
{
  cg::grid_group grid = cg::this_grid();
  __shared__ __align__(16) ushort SB[16384];   // 32 KB, reused by every phase

  cvt_phase(a.hs, a.Wq, a.Wk, a.Wv, a.Wo, a.X, a.nX, a.DD);
  grid.sync();

  for (int job = blockIdx.x; job < NJ_QKV; job += gridDim.x) {
    __syncthreads();   // prior job's LDS reads done before prologue staging
    qkv_job(job, a.X, a.W4, a.bq, a.bv, a.cu, a.qb, a.kb, a.vt, a.T, SB, SB + 8192);
  }
  grid.sync();

  for (int job = blockIdx.x; job < NJ_ATTN; job += gridDim.x)
    attn_job(job, a.qb, a.kb, a.vt, a.X /*ob*/, a.cu, SB);
  grid.sync();

  for (int job = blockIdx.x; job < NJ_OUT; job += gridDim.x) {
    __syncthreads();
    out_job(job, a.X /*ob*/, a.W4 + 3 * (size_t)a.DD, a.bo, a.out, a.T, SB, SB + 8192);
  }
}

// ---------------- fallback standalone kernels (exact R6 semantics) ----------------
__global__ void __launch_bounds__(256)
cvt_all_k(const float* hs, const float* Wq, const float* Wk, const float* Wv,
          const float* Wo, ushort* dst, int nX, int DD) {
  cvt_phase(hs, Wq, Wk, Wv, Wo, dst, nX, DD);
}

__global__ void __launch_bounds__(256, 4)
gemm_qkv_k(const ushort* X, const ushort* W4, const float* bq, const float* bv,
           const int* cu, ushort* qb, ushort* kb, ushort* vt, int M) {
  __shared__ __align__(16) ushort SB[16384];
  const int wg = blockIdx.x;
  if (wg >= 30) return;
  qkv_job(wg * 47 + blockIdx.y, X, W4, bq, bv, cu, qb, kb, vt, M, SB, SB + 8192);
}

__global__ void __launch_bounds__(256, 4)
attn_k(const ushort* qb, const ushort* kb, const ushort* vt, ushort* ob, const int* cu) {
  __shared__ __align__(16) ushort SB[16384];
  attn_job(blockIdx.y * 80 + blockIdx.x, qb, kb, vt, ob, cu, SB);
}

__global__ void __launch_bounds__(256, 4)
gemm_out_k(const ushort* A, const ushort* W, const float* bias, float* out, int M) {
  __shared__ __align__(16) ushort SB[16384];
  out_job(blockIdx.x * 47 + blockIdx.y, A, W, bias, out, M, SB, SB + 8192);
}

// ---------------- launch ----------------
extern "C" void kernel_launch(void* const* d_in, const int* in_sizes, int n_in,
                              void* d_out, int out_size, void* d_ws, size_t ws_size,
                              hipStream_t stream)
{
  (void)n_in; (void)out_size; (void)ws_size;
  const float* hs = (const float*)d_in[0];
  const int*   cu = (const int*)d_in[1];
  const float* Wq = (const float*)d_in[2];
  const float* bq = (const float*)d_in[3];
  const float* Wk = (const float*)d_in[4];
  const float* Wv = (const float*)d_in[5];
  const float* bv = (const float*)d_in[6];
  const float* Wo = (const float*)d_in[7];
  const float* bo = (const float*)d_in[8];
  float* out = (float*)d_out;
  const int T  = in_sizes[0] / DMODEL;            // 6000
  const int DD = DMODEL * DMODEL;
  const int nX = T * DMODEL;

  // workspace layout (ushort elements) — identical to R6:
  //   [0]      X bf16 [T,D]   (reused as ob after gemm_qkv)
  //   [nX]     W4 bf16 [4][D,D]
  //   [+4DD]   qb [T,D]
  //   [+T*D]   kb [T,D]
  //   [+T*D]   vt [D][NSEG][SPAD]   (last region: attn OOB row reads stay inside ws)
  ushort* ws  = (ushort*)d_ws;
  ushort* X   = ws;
  ushort* W4  = X + (size_t)nX;
  ushort* qb  = W4 + 4 * (size_t)DD;
  ushort* kb  = qb + (size_t)T * DMODEL;
  ushort* vt  = kb + (size_t)T * DMODEL;

  MegaArgs ma;
  ma.hs = hs; ma.Wq = Wq; ma.Wk = Wk; ma.Wv = Wv; ma.Wo = Wo;
  ma.bq = bq; ma.bv = bv; ma.bo = bo; ma.cu = cu; ma.out = out;
  ma.X = X; ma.W4 = W4; ma.qb = qb; ma.kb = kb; ma.vt = vt;
  ma.T = T; ma.nX = nX; ma.DD = DD;

  int maxb = 0;
  hipError_t oe = hipOccupancyMaxActiveBlocksPerMultiprocessor(&maxb, mega, 256, 0);
  bool coop_done = false;
  if (oe == hipSuccess && maxb >= 1) {
    const int nb = (maxb < 4 ? maxb : 4) * 256;   // co-resident persistent blocks
    void* args[] = { (void*)&ma };
    hipError_t le = hipLaunchCooperativeKernel((const void*)mega, dim3(nb), dim3(256),
                                               args, 0, stream);
    if (le == hipSuccess) coop_done = true;
    else (void)hipGetLastError();                 // clear error, fall back
  } else {
    (void)hipGetLastError();
  }

  if (!coop_done) {
    // R6-equivalent 4-dispatch fallback
    cvt_all_k<<<2048, 256, 0, stream>>>(hs, Wq, Wk, Wv, Wo, ws, nX, DD);
    gemm_qkv_k<<<dim3(32, 47), 256, 0, stream>>>(X, W4, bq, bv, cu, qb, kb, vt, T);
    attn_k<<<dim3(80, 12), 256, 0, stream>>>(qb, kb, vt, X /*ob*/, cu);
    gemm_out_k<<<dim3(10, 47), 256, 0, stream>>>(X /*ob*/, W4 + 3 * (size_t)DD, bo, out, T);
  }
}

// Round 9
// 303.799 us; speedup vs baseline: 1.7547x; 1.7547x over previous
//
#include <hip/hip_runtime.h>
#include <stdint.h>
#include <math.h>

#define DMODEL 1280
#define NHEAD  20
#define DHEAD  64
#define NSEG   4
#define MAXS   1500
#define SPAD   1536              // padded per-segment kv length (multiple of 64)
#define TPAD   (NSEG*SPAD)       // 6144
#define QT256  ((MAXS + 255) / 256)  // 6 q-tiles for attention (256 q-rows/block)
#define BM 128
#define BN 128
#define BK 32
#define OBM 64                   // gemm_out tile (2-wave blocks)
#define OBN 128
#define QSCALE 0.18033688011112042f  // 0.125 * log2(e): fold softmax scale+log2e into Q
#define NEGV  -1e30f

typedef float  f32x4  __attribute__((ext_vector_type(4)));
typedef __bf16 bf16x8 __attribute__((ext_vector_type(8)));

#if __has_builtin(__builtin_amdgcn_exp2f)
#define EXP2F(x) __builtin_amdgcn_exp2f(x)
#else
#define EXP2F(x) exp2f(x)
#endif

__device__ __forceinline__ ushort f2bf(float f) {
  union { float f; uint32_t u; } a; a.f = f;
  uint32_t u = a.u;
  u += 0x7FFFu + ((u >> 16) & 1u);   // RNE
  return (ushort)(u >> 16);
}

// async global->LDS, 16B per lane: lane i lands at lds + i*16 (wave-uniform base).
__device__ __forceinline__ void async16(const void* g, void* lds) {
  __builtin_amdgcn_global_load_lds((const __attribute__((address_space(1))) void*)g,
                                   (__attribute__((address_space(3))) void*)lds,
                                   16, 0, 0);
}

// kv permutation within each 32-block of the transposed-V layout:
// stored position p <-> actual offset a, p = ((a>>2)&3)*8 + ((a>>4)&1)*4 + (a&3)
__device__ __forceinline__ int perm32(int a) {
  return ((a >> 2) & 3) * 8 + ((a >> 4) & 1) * 4 + (a & 3);
}

// raw barrier (no vmcnt drain); memory clobbers pin LDS op order across it
#define GBAR()  do { asm volatile("" ::: "memory"); __builtin_amdgcn_s_barrier(); \
                     asm volatile("" ::: "memory"); } while (0)
#define WAITV(n) asm volatile("s_waitcnt vmcnt(" #n ")" ::: "memory")

// ---------------- fused fp32 -> bf16 convert (R6-proven: grid-stride, 32B/thread) --------
__global__ void __launch_bounds__(256)
cvt_all(const float* __restrict__ hs, const float* __restrict__ Wq,
        const float* __restrict__ Wk, const float* __restrict__ Wv,
        const float* __restrict__ Wo, ushort* __restrict__ dst, int nX, int DD) {
  const int ng = (nX + 4 * DD) >> 3;
  const int stride = gridDim.x * 256;
  for (int g = blockIdx.x * 256 + threadIdx.x; g < ng; g += stride) {
    const int i = g << 3;
    const float* src;
    if (i < nX) {
      src = hs + i;
    } else {
      const int j = i - nX;
      const int z = (j >= DD) + (j >= 2 * DD) + (j >= 3 * DD);
      const float* w = (z == 0) ? Wq : (z == 1) ? Wk : (z == 2) ? Wv : Wo;
      src = w + (j - z * DD);
    }
    const float4 v0 = ((const float4*)src)[0];
    const float4 v1 = ((const float4*)src)[1];
    ushort4 o0, o1;
    o0.x = f2bf(v0.x); o0.y = f2bf(v0.y); o0.z = f2bf(v0.z); o0.w = f2bf(v0.w);
    o1.x = f2bf(v1.x); o1.y = f2bf(v1.y); o1.z = f2bf(v1.z); o1.w = f2bf(v1.w);
    ((ushort4*)(dst + i))[0] = o0;
    ((ushort4*)(dst + i))[1] = o1;
  }
}

// ---------------- GEMM mainloop (C = A[M,K] * W[N,K]^T) ----------------
// (R2-proven structure: 128x128 tile, 2-buffer global_load_lds, ~2.3 blocks/CU)
// LDS tile: 64 super-rows (2 K-rows) x 8 chunks of 16B, chunk pos p' = p ^ (sr&7);
// 128B super-rows + 3-bit XOR measured 0 bank conflicts.
__device__ __forceinline__ void gemm_tile_mainloop(
    const ushort* __restrict__ A, const ushort* __restrict__ W,
    int M, int m0, int n0, ushort* As, ushort* Bs, f32x4 (&acc)[4][4])
{
  const int tid  = threadIdx.x;
  const int wave = tid >> 6, lane = tid & 63;
  const int quad = lane >> 4, c16 = lane & 15;
  const int wr = (wave >> 1) * 64, wc = (wave & 1) * 64;

  const int M0 = wave * 128 + lane, M1 = M0 + 64;
  const int sr0 = M0 >> 3, pp0 = M0 & 7, p0 = pp0 ^ (sr0 & 7);
  const int sr1 = M1 >> 3, pp1 = M1 & 7, p1 = pp1 ^ (sr1 & 7);
  const int row0 = sr0 * 2 + (p0 >> 2), kc0 = (p0 & 3) << 3;
  const int row1 = sr1 * 2 + (p1 >> 2), kc1 = (p1 & 3) << 3;
  // no row clamp: OOB rows (m-edge tile) read into the next ws region; results masked at store
  const ushort* Ap0 = A + (size_t)(m0 + row0) * DMODEL + kc0;
  const ushort* Ap1 = A + (size_t)(m0 + row1) * DMODEL + kc1;
  const ushort* Bp0 = W + (size_t)(n0 + row0) * DMODEL + kc0;
  const ushort* Bp1 = W + (size_t)(n0 + row1) * DMODEL + kc1;
  const int o0 = wave * 1024;
  const int o1 = wave * 1024 + 512;
  const int BUF = BM * BK;           // 4096 ushorts per buffer

  async16(Ap0, As + o0); async16(Ap1, As + o1);
  async16(Bp0, Bs + o0); async16(Bp1, Bs + o1);

  int c = 0;
  for (int k0 = 0; k0 < DMODEL; k0 += BK, c ^= 1) {
    __syncthreads();                 // publishes buf c (drains the staging loads)
    if (k0 + BK < DMODEL) {
      const int kn = k0 + BK;
      const int bo = (c ^ 1) * BUF;
      async16(Ap0 + kn, As + bo + o0); async16(Ap1 + kn, As + bo + o1);
      async16(Bp0 + kn, Bs + bo + o0); async16(Bp1 + kn, Bs + bo + o1);
    }
    const ushort* Ab = As + c * BUF;
    const ushort* Bb = Bs + c * BUF;
    bf16x8 a[4], b[4];
#pragma unroll
    for (int i = 0; i < 4; ++i) {
      const int row = wr + i * 16 + c16;
      const int sr = row >> 1;
      const int off = (sr << 6) + (((((row & 1) << 2) | quad) ^ (sr & 7)) << 3);
      a[i] = *(const bf16x8*)(Ab + off);
    }
#pragma unroll
    for (int j = 0; j < 4; ++j) {
      const int row = wc + j * 16 + c16;
      const int sr = row >> 1;
      const int off = (sr << 6) + (((((row & 1) << 2) | quad) ^ (sr & 7)) << 3);
      b[j] = *(const bf16x8*)(Bb + off);
    }
#pragma unroll
    for (int i = 0; i < 4; ++i)
#pragma unroll
      for (int j = 0; j < 4; ++j)
        acc[i][j] = __builtin_amdgcn_mfma_f32_16x16x32_bf16(a[i], b[j], acc[i][j], 0, 0, 0);
  }
}

// ---------------- fused QKV projection, bf16 out (R6-proven, 103 us) ----------------
// grid (32, 47): x = weight-group (z*10 + ntile; stride-8 XCD pinning), y = m-tile
__global__ void __launch_bounds__(256, 4)
gemm_qkv(const ushort* __restrict__ X, const ushort* __restrict__ W4,
         const float* __restrict__ bq, const float* __restrict__ bv,
         const int* __restrict__ cu,
         ushort* __restrict__ qb, ushort* __restrict__ kb, ushort* __restrict__ vt, int M)
{
  __shared__ ushort As[2 * BM * BK], Bs[2 * BN * BK];
  const int wg = blockIdx.x;
  if (wg >= 30) return;
  const int z = wg / 10;
  const int n0 = (wg % 10) * BN;
  const int m0 = blockIdx.y * BM;
  const ushort* W = W4 + (size_t)z * DMODEL * DMODEL;

  f32x4 acc[4][4];
  f32x4 zero = {0.f, 0.f, 0.f, 0.f};
#pragma unroll
  for (int i = 0; i < 4; ++i)
#pragma unroll
    for (int j = 0; j < 4; ++j) acc[i][j] = zero;

  gemm_tile_mainloop(X, W, M, m0, n0, As, Bs, acc);

  const int tid = threadIdx.x, wave = tid >> 6, lane = tid & 63;
  const int quad = lane >> 4, c16 = lane & 15;
  const int wr = (wave >> 1) * 64, wc = (wave & 1) * 64;

  if (z == 2) {
    // V: write directly into transposed + kv-permuted layout vt[D][NSEG][SPAD]
    const int c1 = cu[1], c2 = cu[2], c3 = cu[3];
#pragma unroll
    for (int i = 0; i < 4; ++i) {
      const int t0 = m0 + wr + i * 16 + quad * 4;
      const int s0a = (t0 >= c1) + (t0 >= c2) + (t0 >= c3);
      const int s3a = (t0 + 3 >= c1) + (t0 + 3 >= c2) + (t0 + 3 >= c3);
      const int seg0 = (s0a == 0) ? 0 : (s0a == 1) ? c1 : (s0a == 2) ? c2 : c3;
#pragma unroll
      for (int j = 0; j < 4; ++j) {
        const int cfeat = n0 + wc + j * 16 + c16;
        const float bb = bv[cfeat];
        if (t0 + 3 < M && s0a == s3a) {
          const int s = t0 - seg0;                 // s ≡ t0 (mod 4): boundaries are mult of 4
          const size_t base = (size_t)cfeat * TPAD + (size_t)s0a * SPAD
                            + (size_t)(s & ~31) + perm32(s & 31);
          ushort4 w;
          w.x = f2bf(acc[i][j][0] + bb);
          w.y = f2bf(acc[i][j][1] + bb);
          w.z = f2bf(acc[i][j][2] + bb);
          w.w = f2bf(acc[i][j][3] + bb);
          *(ushort4*)(vt + base) = w;
        } else {
#pragma unroll
          for (int r = 0; r < 4; ++r) {
            const int t = t0 + r;
            if (t < M) {
              const int sb = (t >= c1) + (t >= c2) + (t >= c3);
              const int sg = (sb == 0) ? 0 : (sb == 1) ? c1 : (sb == 2) ? c2 : c3;
              const int s = t - sg;
              vt[(size_t)cfeat * TPAD + (size_t)sb * SPAD + (s & ~31) + perm32(s & 31)]
                  = f2bf(acc[i][j][r] + bb);
            }
          }
        }
      }
    }
  } else {
    ushort* out = (z == 0) ? qb : kb;
    const float* bias = (z == 0) ? bq : (const float*)nullptr;
    const float oscale = (z == 0) ? QSCALE : 1.0f;
#pragma unroll
    for (int i = 0; i < 4; ++i) {
      const int rbase = m0 + wr + i * 16 + quad * 4;
#pragma unroll
      for (int j = 0; j < 4; ++j) {
        const int c = n0 + wc + j * 16 + c16;
        const float bb = bias ? bias[c] : 0.f;
#pragma unroll
        for (int r = 0; r < 4; ++r) {
          const int rr = rbase + r;
          if (rr < M) out[(size_t)rr * DMODEL + c] = f2bf((acc[i][j][r] + bb) * oscale);
        }
      }
    }
  }
}

// ---------------- output projection, fp32 out: 64x128 tile, 2-wave blocks (R6) ----------
__global__ void __launch_bounds__(128, 3)
gemm_out(const ushort* __restrict__ A, const ushort* __restrict__ W,
         const float* __restrict__ bias, float* __restrict__ out, int M)
{
  __shared__ __align__(16) ushort As[2 * OBM * BK], Bs[2 * OBN * BK];   // 8 KB + 16 KB
  const int n0 = blockIdx.x * OBN;
  const int m0 = blockIdx.y * OBM;
  const int tid = threadIdx.x, wave = tid >> 6, lane = tid & 63;
  const int quad = lane >> 4, c16 = lane & 15;

  int rA[2], kA[2], rB[4], kB[4];
#pragma unroll
  for (int q = 0; q < 2; ++q) {
    const int s = tid + q * 128;
    const int sr = s >> 3, p = (s & 7) ^ (sr & 7);
    rA[q] = sr * 2 + (p >> 2); kA[q] = (p & 3) << 3;
  }
#pragma unroll
  for (int q = 0; q < 4; ++q) {
    const int s = tid + q * 128;
    const int sr = s >> 3, p = (s & 7) ^ (sr & 7);
    rB[q] = sr * 2 + (p >> 2); kB[q] = (p & 3) << 3;
  }
  // OOB m-edge rows read into the next ws region; masked at store
  const ushort* ApS0 = A + (size_t)(m0 + rA[0]) * DMODEL + kA[0];
  const ushort* ApS1 = A + (size_t)(m0 + rA[1]) * DMODEL + kA[1];
  const ushort* BpS0 = W + (size_t)(n0 + rB[0]) * DMODEL + kB[0];
  const ushort* BpS1 = W + (size_t)(n0 + rB[1]) * DMODEL + kB[1];
  const ushort* BpS2 = W + (size_t)(n0 + rB[2]) * DMODEL + kB[2];
  const ushort* BpS3 = W + (size_t)(n0 + rB[3]) * DMODEL + kB[3];
  const int aO0 = (wave * 64) * 8,       aO1 = (128 + wave * 64) * 8;
  const int bO0 = (wave * 64) * 8,       bO1 = (128 + wave * 64) * 8;
  const int bO2 = (256 + wave * 64) * 8, bO3 = (384 + wave * 64) * 8;
  const int BUFA = OBM * BK;   // 2048 ushorts
  const int BUFB = OBN * BK;   // 4096 ushorts

#define OSTAGE(c, kk) do { \
    ushort* Ad = As + (c) * BUFA; ushort* Bd = Bs + (c) * BUFB; \
    async16(ApS0 + (kk), Ad + aO0); async16(ApS1 + (kk), Ad + aO1); \
    async16(BpS0 + (kk), Bd + bO0); async16(BpS1 + (kk), Bd + bO1); \
    async16(BpS2 + (kk), Bd + bO2); async16(BpS3 + (kk), Bd + bO3); \
  } while (0)

  f32x4 acc[4][4];
  f32x4 zero = {0.f, 0.f, 0.f, 0.f};
#pragma unroll
  for (int i = 0; i < 4; ++i)
#pragma unroll
    for (int j = 0; j < 4; ++j) acc[i][j] = zero;

  OSTAGE(0, 0);
  int c = 0;
  for (int k0 = 0; k0 < DMODEL; k0 += BK, c ^= 1) {
    __syncthreads();                 // publishes buf c
    if (k0 + BK < DMODEL) OSTAGE(c ^ 1, k0 + BK);
    const ushort* Ab = As + c * BUFA;
    const ushort* Bb = Bs + c * BUFB;
    bf16x8 a[4], b[4];
#pragma unroll
    for (int i = 0; i < 4; ++i) {            // A rows 0..63 (shared by both waves)
      const int row = i * 16 + c16;
      const int sr = row >> 1;
      const int off = (sr << 6) + (((((row & 1) << 2) | quad) ^ (sr & 7)) << 3);
      a[i] = *(const bf16x8*)(Ab + off);
    }
#pragma unroll
    for (int j = 0; j < 4; ++j) {            // B rows wave*64 .. wave*64+63
      const int row = wave * 64 + j * 16 + c16;
      const int sr = row >> 1;
      const int off = (sr << 6) + (((((row & 1) << 2) | quad) ^ (sr & 7)) << 3);
      b[j] = *(const bf16x8*)(Bb + off);
    }
#pragma unroll
    for (int i = 0; i < 4; ++i)
#pragma unroll
      for (int j = 0; j < 4; ++j)
        acc[i][j] = __builtin_amdgcn_mfma_f32_16x16x32_bf16(a[i], b[j], acc[i][j], 0, 0, 0);
  }
#undef OSTAGE

#pragma unroll
  for (int i = 0; i < 4; ++i) {
    const int rbase = m0 + i * 16 + quad * 4;
#pragma unroll
    for (int j = 0; j < 4; ++j) {
      const int cc = n0 + wave * 64 + j * 16 + c16;
      const float bb = bias[cc];
#pragma unroll
      for (int r = 0; r < 4; ++r) {
        const int rr = rbase + r;
        if (rr < M) out[(size_t)rr * DMODEL + cc] = acc[i][j][r] + bb;
      }
    }
  }
}

// ---------------- fused flash attention (8-wave, 256 q-rows/block) ----------------
// R9 change: triple-buffered K/V with counted vmcnt (T3/T4 pattern). R6's __syncthreads
// drained vmcnt(0) every iter against an L2-miss/L3 latency (~500-900cy) with only a
// 1-iteration (~500cy) prefetch flight and ~1.9 grid-limited blocks/CU -> every wave
// stalled at the barrier. Now: prefetch distance 2 tiles (flight ~1000cy), per iter:
//   GBAR -> stage tile t+2 (2 async16/thread) -> vmcnt(4) [= tiles t+1,t+2 in flight,
//   tile t guaranteed landed] -> GBAR -> compute tile t.
// Safety: each wave's ds_reads are consumed by MFMA before it reaches barrier 1 (lgkm
// forced), so all reads of buf (t-1)%3 complete before any tile-t+2 write to it;
// barrier 2 makes per-wave vmcnt a collective guarantee before any ds_read of tile t.
// LDS 48 KB (Kb[3] + Vb[3]); Q staged in the first 32 KB then recycled. VGPR unchanged.
// grid: (NSEG*NHEAD, QT256): x = head-seg (pins all q-tiles of one (b,h) to one XCD)
__global__ void __launch_bounds__(512, 4)
attn_fused(const ushort* __restrict__ qb, const ushort* __restrict__ kb,
           const ushort* __restrict__ vt, ushort* __restrict__ ob,
           const int* __restrict__ cu, int T)
{
  __shared__ ushort SB[24576];     // 48 KB: Kb[3] @ {0,4096,8192}, Vb[3] @ 12288 + {0,4096,8192}
  const int hs = blockIdx.x;
  const int b = hs / NHEAD, h = hs % NHEAD;
  const int seg0 = cu[b];
  const int len  = cu[b + 1] - seg0;
  const int q0 = blockIdx.y * 256;
  if (q0 >= len) return;
  const int tid = threadIdx.x, wave = tid >> 6, lane = tid & 63;
  const int quad = lane >> 4, c16 = lane & 15;

  // ---- stage Q (256 rows x 64 d = 32KB) into SB[0..16383], pre-swizzled-global chunks ----
#pragma unroll
  for (int t = 0; t < 4; ++t) {
    const int slot = t * 512 + tid;
    const int r = slot >> 3, k2 = slot & 7;
    const int col = ((k2 ^ (r & 7)) << 3);
    async16(qb + (size_t)(seg0 + q0 + r) * DMODEL + h * DHEAD + col,
            &SB[(t * 512 + wave * 64) * 8]);
  }

  // ---- per-lane K/V staging pointers (512 threads cover 64 rows x 8 chunks) ----
  const int rK = tid >> 3, kK = tid & 7;
  const int colK = ((kK ^ (rK & 7)) << 3);
  const ushort* kp = kb + (size_t)(seg0 + rK) * DMODEL + h * DHEAD + colK;
  const ushort* vp = vt + (size_t)(h * DHEAD + rK) * TPAD + (size_t)b * SPAD + colK;
  const int ldsoff = wave * 512;   // ushort offset of this wave's 64 staging slots

  __syncthreads();   // Q published (drains vmcnt)

  // Q fragments -> registers; SB is dead afterwards (recycled as kv triple-buffer)
  bf16x8 aq[2][2];
#pragma unroll
  for (int n = 0; n < 2; ++n)
#pragma unroll
    for (int ks = 0; ks < 2; ++ks) {
      const int row = wave * 32 + n * 16 + c16;
      aq[n][ks] = *(const bf16x8*)(&SB[row * 64 + (((ks * 4 + quad) ^ (c16 & 7)) << 3)]);
    }

  __syncthreads();   // all Q reads complete; SB reusable

  // prologue: stage kv tiles 0 and 1 (K -> Kb[t], V -> Vb[t])
  async16(kp, &SB[ldsoff]);
  async16(vp, &SB[12288 + ldsoff]);
  async16(kp + (size_t)64 * DMODEL, &SB[4096 + ldsoff]);
  async16(vp + 64, &SB[12288 + 4096 + ldsoff]);
  kp += (size_t)128 * DMODEL; vp += 128;

  float l_i[2] = {0.f, 0.f};
  f32x4 o_acc[2][4];
  f32x4 zero = {0.f, 0.f, 0.f, 0.f};
#pragma unroll
  for (int n = 0; n < 2; ++n)
#pragma unroll
    for (int m = 0; m < 4; ++m) o_acc[n][m] = zero;

  __syncthreads();   // one-time full drain: tiles 0 and 1 resident

  const int niter = (len + 63) >> 6;
  int bcur = 0;                      // buffer index = it % 3 (rotating counter)
  for (int it = 0; it < niter; ++it) {
    GBAR();            // all waves done with iter it-1's LDS reads (MFMA-forced lgkm)
    if (it + 2 < niter) {
      int b2 = bcur + 2; if (b2 >= 3) b2 -= 3;
      async16(kp, &SB[b2 * 4096 + ldsoff]);
      async16(vp, &SB[12288 + b2 * 4096 + ldsoff]);
      kp += (size_t)64 * DMODEL; vp += 64;
      WAITV(4);        // tiles it+1, it+2 (4 loads) stay in flight; tile it landed
    } else if (it + 1 < niter) {
      WAITV(2);        // only tile it+1 in flight
    } else {
      WAITV(0);        // final tile
    }
    GBAR();            // collective: every wave's tile-it loads confirmed landed
    const ushort* Kt = &SB[bcur * 4096];
    const ushort* Vt = &SB[12288 + bcur * 4096];

    // S^T = K * Q^T : A = K-frag (m=kv), B = Q-frag (n=q). C: row(kv)=quad*4+reg, col(q)=c16
    f32x4 s[2][4];
    __builtin_amdgcn_s_setprio(1);
#pragma unroll
    for (int f = 0; f < 4; ++f) {
      const int row = f * 16 + c16;
      const int ch = c16 & 7;
      bf16x8 ak0 = *(const bf16x8*)(Kt + row * 64 + ((quad ^ ch) << 3));
      bf16x8 ak1 = *(const bf16x8*)(Kt + row * 64 + (((4 + quad) ^ ch) << 3));
#pragma unroll
      for (int n = 0; n < 2; ++n) {
        s[n][f] = zero;
        s[n][f] = __builtin_amdgcn_mfma_f32_16x16x32_bf16(ak0, aq[n][0], s[n][f], 0, 0, 0);
        s[n][f] = __builtin_amdgcn_mfma_f32_16x16x32_bf16(ak1, aq[n][1], s[n][f], 0, 0, 0);
      }
    }
    __builtin_amdgcn_s_setprio(0);

    // mask invalid kv (only last iteration; garbage K rows -> masked here)
    const int kv0 = it * 64;
    if (kv0 + 64 > len) {
#pragma unroll
      for (int f = 0; f < 4; ++f) {
        const int kvb = kv0 + f * 16 + quad * 4;
#pragma unroll
        for (int r = 0; r < 4; ++r)
          if (kvb + r >= len) { s[0][f][r] = NEGV; s[1][f][r] = NEGV; }
      }
    }

    // no-max softmax: p = exp2(s) directly (raw v_exp_f32; exp2(-1e30)=0 exactly);
    // per-lane partial l, cross-quad reduction deferred to epilogue
#pragma unroll
    for (int n = 0; n < 2; ++n) {
      float rs = 0.f;
#pragma unroll
      for (int f = 0; f < 4; ++f)
#pragma unroll
        for (int r = 0; r < 4; ++r) {
          const float p = EXP2F(s[n][f][r]);
          s[n][f][r] = p;
          rs += p;
        }
      l_i[n] += rs;
    }

    // pack P^T (registers) as B-operand: slot (quad,j) <-> kv = g*32 + (j>>2)*16 + quad*4 + (j&3)
    // compiler casts fuse to v_cvt_pk_bf16_f32 (proven faster than hand bit-packing)
    bf16x8 bp[2][2];
#pragma unroll
    for (int n = 0; n < 2; ++n)
#pragma unroll
      for (int g = 0; g < 2; ++g) {
        bf16x8 t;
#pragma unroll
        for (int r = 0; r < 4; ++r) {
          t[r]     = (__bf16)s[n][2 * g][r];
          t[r + 4] = (__bf16)s[n][2 * g + 1][r];
        }
        bp[n][g] = t;
      }

    // O^T += V^T * P^T : A = V^T-frag (m=d), B = P^T (regs). C: row(d)=quad*4+reg, col(q)=c16
    __builtin_amdgcn_s_setprio(1);
#pragma unroll
    for (int m = 0; m < 4; ++m) {
      const int row = m * 16 + c16;
      const int ch = c16 & 7;
      bf16x8 av0 = *(const bf16x8*)(Vt + row * 64 + ((quad ^ ch) << 3));
      bf16x8 av1 = *(const bf16x8*)(Vt + row * 64 + (((4 + quad) ^ ch) << 3));
#pragma unroll
      for (int n = 0; n < 2; ++n) {
        o_acc[n][m] = __builtin_amdgcn_mfma_f32_16x16x32_bf16(av0, bp[n][0], o_acc[n][m], 0, 0, 0);
        o_acc[n][m] = __builtin_amdgcn_mfma_f32_16x16x32_bf16(av1, bp[n][1], o_acc[n][m], 0, 0, 0);
      }
    }
    __builtin_amdgcn_s_setprio(0);

    bcur = (bcur == 2) ? 0 : bcur + 1;
  }

  // epilogue: reduce l across quads, normalize, store bf16.
  // O^T: d = m*16+quad*4+r, q = wave*32+n*16+c16
#pragma unroll
  for (int n = 0; n < 2; ++n) {
    float l = l_i[n];
    l += __shfl_xor(l, 16);
    l += __shfl_xor(l, 32);
    const int q = q0 + wave * 32 + n * 16 + c16;
    if (q < len) {
      const float inv = 1.0f / l;
      const size_t base = (size_t)(seg0 + q) * DMODEL + h * DHEAD;
#pragma unroll
      for (int m = 0; m < 4; ++m) {
        ushort4 pk;
        pk.x = f2bf(o_acc[n][m][0] * inv);
        pk.y = f2bf(o_acc[n][m][1] * inv);
        pk.z = f2bf(o_acc[n][m][2] * inv);
        pk.w = f2bf(o_acc[n][m][3] * inv);
        *(ushort4*)(ob + base + m * 16 + quad * 4) = pk;
      }
    }
  }
}

// ---------------- launch ----------------
extern "C" void kernel_launch(void* const* d_in, const int* in_sizes, int n_in,
                              void* d_out, int out_size, void* d_ws, size_t ws_size,
                              hipStream_t stream)
{
  (void)n_in; (void)out_size; (void)ws_size;
  const float* hs = (const float*)d_in[0];
  const int*   cu = (const int*)d_in[1];
  const float* Wq = (const float*)d_in[2];
  const float* bq = (const float*)d_in[3];
  const float* Wk = (const float*)d_in[4];
  const float* Wv = (const float*)d_in[5];
  const float* bv = (const float*)d_in[6];
  const float* Wo = (const float*)d_in[7];
  const float* bo = (const float*)d_in[8];
  float* out = (float*)d_out;
  const int T  = in_sizes[0] / DMODEL;            // 6000
  const int DD = DMODEL * DMODEL;
  const int nX = T * DMODEL;

  // workspace layout (ushort elements):
  //   [0]      X bf16 [T,D]   (reused as ob after gemm_qkv)
  //   [nX]     W4 bf16 [4][D,D]
  //   [+4DD]   qb [T,D]
  //   [+T*D]   kb [T,D]
  //   [+T*D]   vt [D][NSEG][SPAD]   (last region: attn OOB row reads stay inside ws)
  ushort* ws  = (ushort*)d_ws;
  ushort* X   = ws;
  ushort* W4  = X + (size_t)nX;
  ushort* qb  = W4 + 4 * (size_t)DD;
  ushort* kb  = qb + (size_t)T * DMODEL;
  ushort* vt  = kb + (size_t)T * DMODEL;
  ushort* ob  = X;                                // X dead after gemm_qkv

  cvt_all<<<2048, 256, 0, stream>>>(hs, Wq, Wk, Wv, Wo, ws, nX, DD);

  gemm_qkv<<<dim3(32, (T + BM - 1) / BM), 256, 0, stream>>>(
      X, W4, bq, bv, cu, qb, kb, vt, T);

  attn_fused<<<dim3(NSEG * NHEAD, QT256), 512, 0, stream>>>(qb, kb, vt, ob, cu, T);

  gemm_out<<<dim3(10, (T + OBM - 1) / OBM), 128, 0, stream>>>(
      ob, W4 + 3 * (size_t)DD, bo, out, T);
}

// Round 10
// 298.636 us; speedup vs baseline: 1.7850x; 1.0173x over previous
//
#include <hip/hip_runtime.h>
#include <stdint.h>
#include <math.h>

#define DMODEL 1280
#define NHEAD  20
#define DHEAD  64
#define NSEG   4
#define MAXS   1500
#define SPAD   1536              // padded per-segment kv length (multiple of 64)
#define TPAD   (NSEG*SPAD)       // 6144
#define QT256  ((MAXS + 255) / 256)  // 6 q-tiles for attention (256 q-rows/block)
#define BM 128
#define BN 128
#define BK 32
#define OBM 64                   // gemm_out tile (2-wave blocks)
#define OBN 128
#define QSCALE 0.18033688011112042f  // 0.125 * log2(e): fold softmax scale+log2e into Q
#define NEGV  -1e30f

typedef float  f32x4  __attribute__((ext_vector_type(4)));
typedef __bf16 bf16x8 __attribute__((ext_vector_type(8)));

#if __has_builtin(__builtin_amdgcn_exp2f)
#define EXP2F(x) __builtin_amdgcn_exp2f(x)
#else
#define EXP2F(x) exp2f(x)
#endif

__device__ __forceinline__ ushort f2bf(float f) {
  union { float f; uint32_t u; } a; a.f = f;
  uint32_t u = a.u;
  u += 0x7FFFu + ((u >> 16) & 1u);   // RNE
  return (ushort)(u >> 16);
}

// async global->LDS, 16B per lane: lane i lands at lds + i*16 (wave-uniform base).
__device__ __forceinline__ void async16(const void* g, void* lds) {
  __builtin_amdgcn_global_load_lds((const __attribute__((address_space(1))) void*)g,
                                   (__attribute__((address_space(3))) void*)lds,
                                   16, 0, 0);
}

// kv permutation within each 32-block of the transposed-V layout:
// stored position p <-> actual offset a, p = ((a>>2)&3)*8 + ((a>>4)&1)*4 + (a&3)
__device__ __forceinline__ int perm32(int a) {
  return ((a >> 2) & 3) * 8 + ((a >> 4) & 1) * 4 + (a & 3);
}

// ---------------- fused fp32 -> bf16 convert (R6-proven: grid-stride, 32B/thread) --------
__global__ void __launch_bounds__(256)
cvt_all(const float* __restrict__ hs, const float* __restrict__ Wq,
        const float* __restrict__ Wk, const float* __restrict__ Wv,
        const float* __restrict__ Wo, ushort* __restrict__ dst, int nX, int DD) {
  const int ng = (nX + 4 * DD) >> 3;
  const int stride = gridDim.x * 256;
  for (int g = blockIdx.x * 256 + threadIdx.x; g < ng; g += stride) {
    const int i = g << 3;
    const float* src;
    if (i < nX) {
      src = hs + i;
    } else {
      const int j = i - nX;
      const int z = (j >= DD) + (j >= 2 * DD) + (j >= 3 * DD);
      const float* w = (z == 0) ? Wq : (z == 1) ? Wk : (z == 2) ? Wv : Wo;
      src = w + (j - z * DD);
    }
    const float4 v0 = ((const float4*)src)[0];
    const float4 v1 = ((const float4*)src)[1];
    ushort4 o0, o1;
    o0.x = f2bf(v0.x); o0.y = f2bf(v0.y); o0.z = f2bf(v0.z); o0.w = f2bf(v0.w);
    o1.x = f2bf(v1.x); o1.y = f2bf(v1.y); o1.z = f2bf(v1.z); o1.w = f2bf(v1.w);
    ((ushort4*)(dst + i))[0] = o0;
    ((ushort4*)(dst + i))[1] = o1;
  }
}

// ---------------- GEMM mainloop (C = A[M,K] * W[N,K]^T) ----------------
// (R2-proven structure: 128x128 tile, 2-buffer global_load_lds, ~2.3 blocks/CU)
// LDS tile: 64 super-rows (2 K-rows) x 8 chunks of 16B, chunk pos p' = p ^ (sr&7);
// 128B super-rows + 3-bit XOR measured 0 bank conflicts.
__device__ __forceinline__ void gemm_tile_mainloop(
    const ushort* __restrict__ A, const ushort* __restrict__ W,
    int M, int m0, int n0, ushort* As, ushort* Bs, f32x4 (&acc)[4][4])
{
  const int tid  = threadIdx.x;
  const int wave = tid >> 6, lane = tid & 63;
  const int quad = lane >> 4, c16 = lane & 15;
  const int wr = (wave >> 1) * 64, wc = (wave & 1) * 64;

  const int M0 = wave * 128 + lane, M1 = M0 + 64;
  const int sr0 = M0 >> 3, pp0 = M0 & 7, p0 = pp0 ^ (sr0 & 7);
  const int sr1 = M1 >> 3, pp1 = M1 & 7, p1 = pp1 ^ (sr1 & 7);
  const int row0 = sr0 * 2 + (p0 >> 2), kc0 = (p0 & 3) << 3;
  const int row1 = sr1 * 2 + (p1 >> 2), kc1 = (p1 & 3) << 3;
  // no row clamp: OOB rows (m-edge tile) read into the next ws region; results masked at store
  const ushort* Ap0 = A + (size_t)(m0 + row0) * DMODEL + kc0;
  const ushort* Ap1 = A + (size_t)(m0 + row1) * DMODEL + kc1;
  const ushort* Bp0 = W + (size_t)(n0 + row0) * DMODEL + kc0;
  const ushort* Bp1 = W + (size_t)(n0 + row1) * DMODEL + kc1;
  const int o0 = wave * 1024;
  const int o1 = wave * 1024 + 512;
  const int BUF = BM * BK;           // 4096 ushorts per buffer

  async16(Ap0, As + o0); async16(Ap1, As + o1);
  async16(Bp0, Bs + o0); async16(Bp1, Bs + o1);

  int c = 0;
  for (int k0 = 0; k0 < DMODEL; k0 += BK, c ^= 1) {
    __syncthreads();                 // publishes buf c (drains the staging loads)
    if (k0 + BK < DMODEL) {
      const int kn = k0 + BK;
      const int bo = (c ^ 1) * BUF;
      async16(Ap0 + kn, As + bo + o0); async16(Ap1 + kn, As + bo + o1);
      async16(Bp0 + kn, Bs + bo + o0); async16(Bp1 + kn, Bs + bo + o1);
    }
    const ushort* Ab = As + c * BUF;
    const ushort* Bb = Bs + c * BUF;
    bf16x8 a[4], b[4];
#pragma unroll
    for (int i = 0; i < 4; ++i) {
      const int row = wr + i * 16 + c16;
      const int sr = row >> 1;
      const int off = (sr << 6) + (((((row & 1) << 2) | quad) ^ (sr & 7)) << 3);
      a[i] = *(const bf16x8*)(Ab + off);
    }
#pragma unroll
    for (int j = 0; j < 4; ++j) {
      const int row = wc + j * 16 + c16;
      const int sr = row >> 1;
      const int off = (sr << 6) + (((((row & 1) << 2) | quad) ^ (sr & 7)) << 3);
      b[j] = *(const bf16x8*)(Bb + off);
    }
#pragma unroll
    for (int i = 0; i < 4; ++i)
#pragma unroll
      for (int j = 0; j < 4; ++j)
        acc[i][j] = __builtin_amdgcn_mfma_f32_16x16x32_bf16(a[i], b[j], acc[i][j], 0, 0, 0);
  }
}

// ---------------- fused QKV projection, bf16 out (R6-proven, ~102 us) ----------------
// grid (32, 47): x = weight-group (z*10 + ntile; stride-8 XCD pinning), y = m-tile
__global__ void __launch_bounds__(256, 4)
gemm_qkv(const ushort* __restrict__ X, const ushort* __restrict__ W4,
         const float* __restrict__ bq, const float* __restrict__ bv,
         const int* __restrict__ cu,
         ushort* __restrict__ qb, ushort* __restrict__ kb, ushort* __restrict__ vt, int M)
{
  __shared__ ushort As[2 * BM * BK], Bs[2 * BN * BK];
  const int wg = blockIdx.x;
  if (wg >= 30) return;
  const int z = wg / 10;
  const int n0 = (wg % 10) * BN;
  const int m0 = blockIdx.y * BM;
  const ushort* W = W4 + (size_t)z * DMODEL * DMODEL;

  f32x4 acc[4][4];
  f32x4 zero = {0.f, 0.f, 0.f, 0.f};
#pragma unroll
  for (int i = 0; i < 4; ++i)
#pragma unroll
    for (int j = 0; j < 4; ++j) acc[i][j] = zero;

  gemm_tile_mainloop(X, W, M, m0, n0, As, Bs, acc);

  const int tid = threadIdx.x, wave = tid >> 6, lane = tid & 63;
  const int quad = lane >> 4, c16 = lane & 15;
  const int wr = (wave >> 1) * 64, wc = (wave & 1) * 64;

  if (z == 2) {
    // V: write directly into transposed + kv-permuted layout vt[D][NSEG][SPAD]
    const int c1 = cu[1], c2 = cu[2], c3 = cu[3];
#pragma unroll
    for (int i = 0; i < 4; ++i) {
      const int t0 = m0 + wr + i * 16 + quad * 4;
      const int s0a = (t0 >= c1) + (t0 >= c2) + (t0 >= c3);
      const int s3a = (t0 + 3 >= c1) + (t0 + 3 >= c2) + (t0 + 3 >= c3);
      const int seg0 = (s0a == 0) ? 0 : (s0a == 1) ? c1 : (s0a == 2) ? c2 : c3;
#pragma unroll
      for (int j = 0; j < 4; ++j) {
        const int cfeat = n0 + wc + j * 16 + c16;
        const float bb = bv[cfeat];
        if (t0 + 3 < M && s0a == s3a) {
          const int s = t0 - seg0;                 // s ≡ t0 (mod 4): boundaries are mult of 4
          const size_t base = (size_t)cfeat * TPAD + (size_t)s0a * SPAD
                            + (size_t)(s & ~31) + perm32(s & 31);
          ushort4 w;
          w.x = f2bf(acc[i][j][0] + bb);
          w.y = f2bf(acc[i][j][1] + bb);
          w.z = f2bf(acc[i][j][2] + bb);
          w.w = f2bf(acc[i][j][3] + bb);
          *(ushort4*)(vt + base) = w;
        } else {
#pragma unroll
          for (int r = 0; r < 4; ++r) {
            const int t = t0 + r;
            if (t < M) {
              const int sb = (t >= c1) + (t >= c2) + (t >= c3);
              const int sg = (sb == 0) ? 0 : (sb == 1) ? c1 : (sb == 2) ? c2 : c3;
              const int s = t - sg;
              vt[(size_t)cfeat * TPAD + (size_t)sb * SPAD + (s & ~31) + perm32(s & 31)]
                  = f2bf(acc[i][j][r] + bb);
            }
          }
        }
      }
    }
  } else {
    ushort* out = (z == 0) ? qb : kb;
    const float* bias = (z == 0) ? bq : (const float*)nullptr;
    const float oscale = (z == 0) ? QSCALE : 1.0f;
#pragma unroll
    for (int i = 0; i < 4; ++i) {
      const int rbase = m0 + wr + i * 16 + quad * 4;
#pragma unroll
      for (int j = 0; j < 4; ++j) {
        const int c = n0 + wc + j * 16 + c16;
        const float bb = bias ? bias[c] : 0.f;
#pragma unroll
        for (int r = 0; r < 4; ++r) {
          const int rr = rbase + r;
          if (rr < M) out[(size_t)rr * DMODEL + c] = f2bf((acc[i][j][r] + bb) * oscale);
        }
      }
    }
  }
}

// ---------------- output projection, fp32 out: 64x128 tile, 2-wave blocks (R6) ----------
__global__ void __launch_bounds__(128, 3)
gemm_out(const ushort* __restrict__ A, const ushort* __restrict__ W,
         const float* __restrict__ bias, float* __restrict__ out, int M)
{
  __shared__ __align__(16) ushort As[2 * OBM * BK], Bs[2 * OBN * BK];   // 8 KB + 16 KB
  const int n0 = blockIdx.x * OBN;
  const int m0 = blockIdx.y * OBM;
  const int tid = threadIdx.x, wave = tid >> 6, lane = tid & 63;
  const int quad = lane >> 4, c16 = lane & 15;

  int rA[2], kA[2], rB[4], kB[4];
#pragma unroll
  for (int q = 0; q < 2; ++q) {
    const int s = tid + q * 128;
    const int sr = s >> 3, p = (s & 7) ^ (sr & 7);
    rA[q] = sr * 2 + (p >> 2); kA[q] = (p & 3) << 3;
  }
#pragma unroll
  for (int q = 0; q < 4; ++q) {
    const int s = tid + q * 128;
    const int sr = s >> 3, p = (s & 7) ^ (sr & 7);
    rB[q] = sr * 2 + (p >> 2); kB[q] = (p & 3) << 3;
  }
  // OOB m-edge rows read into the next ws region; masked at store
  const ushort* ApS0 = A + (size_t)(m0 + rA[0]) * DMODEL + kA[0];
  const ushort* ApS1 = A + (size_t)(m0 + rA[1]) * DMODEL + kA[1];
  const ushort* BpS0 = W + (size_t)(n0 + rB[0]) * DMODEL + kB[0];
  const ushort* BpS1 = W + (size_t)(n0 + rB[1]) * DMODEL + kB[1];
  const ushort* BpS2 = W + (size_t)(n0 + rB[2]) * DMODEL + kB[2];
  const ushort* BpS3 = W + (size_t)(n0 + rB[3]) * DMODEL + kB[3];
  const int aO0 = (wave * 64) * 8,       aO1 = (128 + wave * 64) * 8;
  const int bO0 = (wave * 64) * 8,       bO1 = (128 + wave * 64) * 8;
  const int bO2 = (256 + wave * 64) * 8, bO3 = (384 + wave * 64) * 8;
  const int BUFA = OBM * BK;   // 2048 ushorts
  const int BUFB = OBN * BK;   // 4096 ushorts

#define OSTAGE(c, kk) do { \
    ushort* Ad = As + (c) * BUFA; ushort* Bd = Bs + (c) * BUFB; \
    async16(ApS0 + (kk), Ad + aO0); async16(ApS1 + (kk), Ad + aO1); \
    async16(BpS0 + (kk), Bd + bO0); async16(BpS1 + (kk), Bd + bO1); \
    async16(BpS2 + (kk), Bd + bO2); async16(BpS3 + (kk), Bd + bO3); \
  } while (0)

  f32x4 acc[4][4];
  f32x4 zero = {0.f, 0.f, 0.f, 0.f};
#pragma unroll
  for (int i = 0; i < 4; ++i)
#pragma unroll
    for (int j = 0; j < 4; ++j) acc[i][j] = zero;

  OSTAGE(0, 0);
  int c = 0;
  for (int k0 = 0; k0 < DMODEL; k0 += BK, c ^= 1) {
    __syncthreads();                 // publishes buf c
    if (k0 + BK < DMODEL) OSTAGE(c ^ 1, k0 + BK);
    const ushort* Ab = As + c * BUFA;
    const ushort* Bb = Bs + c * BUFB;
    bf16x8 a[4], b[4];
#pragma unroll
    for (int i = 0; i < 4; ++i) {            // A rows 0..63 (shared by both waves)
      const int row = i * 16 + c16;
      const int sr = row >> 1;
      const int off = (sr << 6) + (((((row & 1) << 2) | quad) ^ (sr & 7)) << 3);
      a[i] = *(const bf16x8*)(Ab + off);
    }
#pragma unroll
    for (int j = 0; j < 4; ++j) {            // B rows wave*64 .. wave*64+63
      const int row = wave * 64 + j * 16 + c16;
      const int sr = row >> 1;
      const int off = (sr << 6) + (((((row & 1) << 2) | quad) ^ (sr & 7)) << 3);
      b[j] = *(const bf16x8*)(Bb + off);
    }
#pragma unroll
    for (int i = 0; i < 4; ++i)
#pragma unroll
      for (int j = 0; j < 4; ++j)
        acc[i][j] = __builtin_amdgcn_mfma_f32_16x16x32_bf16(a[i], b[j], acc[i][j], 0, 0, 0);
  }
#undef OSTAGE

#pragma unroll
  for (int i = 0; i < 4; ++i) {
    const int rbase = m0 + i * 16 + quad * 4;
#pragma unroll
    for (int j = 0; j < 4; ++j) {
      const int cc = n0 + wave * 64 + j * 16 + c16;
      const float bb = bias[cc];
#pragma unroll
      for (int r = 0; r < 4; ++r) {
        const int rr = rbase + r;
        if (rr < M) out[(size_t)rr * DMODEL + cc] = acc[i][j][r] + bb;
      }
    }
  }
}

// ---------------- fused flash attention (8-wave, 256 q-rows/block) ----------------
// R6-proven structure restored (double-buffer + __syncthreads: R9's counted-vmcnt 3-buf
// was null — attn's 15 waves/CU of TLP already hides prefetch latency).
// R10 change: l-accumulation as 4 independent partial chains per n. The old `rs += p`
// was a 32-deep serial float-add chain (~128 cyc dep latency per n per iter) on the
// QK->PV critical path that the compiler cannot reassociate without fast-math.
// LDS = 32 KB total: Q staged in all of it, then recycled as KV dbuf [2][8192 ushorts].
// grid: (NSEG*NHEAD, QT256): x = head-seg (pins all q-tiles of one (b,h) to one XCD)
__global__ void __launch_bounds__(512, 4)
attn_fused(const ushort* __restrict__ qb, const ushort* __restrict__ kb,
           const ushort* __restrict__ vt, ushort* __restrict__ ob,
           const int* __restrict__ cu, int T)
{
  __shared__ ushort SB[16384];     // 32 KB
  const int hs = blockIdx.x;
  const int b = hs / NHEAD, h = hs % NHEAD;
  const int seg0 = cu[b];
  const int len  = cu[b + 1] - seg0;
  const int q0 = blockIdx.y * 256;
  if (q0 >= len) return;
  const int tid = threadIdx.x, wave = tid >> 6, lane = tid & 63;
  const int quad = lane >> 4, c16 = lane & 15;

  // ---- stage Q (256 rows x 64 d = 32KB) into SB, pre-swizzled-global chunks ----
#pragma unroll
  for (int t = 0; t < 4; ++t) {
    const int slot = t * 512 + tid;
    const int r = slot >> 3, k2 = slot & 7;
    const int col = ((k2 ^ (r & 7)) << 3);
    async16(qb + (size_t)(seg0 + q0 + r) * DMODEL + h * DHEAD + col,
            &SB[(t * 512 + wave * 64) * 8]);
  }

  // ---- per-lane K/V staging pointers (512 threads cover 64 rows x 8 chunks) ----
  const int rK = tid >> 3, kK = tid & 7;
  const int colK = ((kK ^ (rK & 7)) << 3);
  const ushort* kp = kb + (size_t)(seg0 + rK) * DMODEL + h * DHEAD + colK;
  const ushort* vp = vt + (size_t)(h * DHEAD + rK) * TPAD + (size_t)b * SPAD + colK;
  const int ldsoff = wave * 512;   // ushort offset of this wave's 64 staging slots

  __syncthreads();   // Q published (drains vmcnt)

  // Q fragments -> registers; SB is dead afterwards (recycled as kv double-buffer)
  bf16x8 aq[2][2];
#pragma unroll
  for (int n = 0; n < 2; ++n)
#pragma unroll
    for (int ks = 0; ks < 2; ++ks) {
      const int row = wave * 32 + n * 16 + c16;
      aq[n][ks] = *(const bf16x8*)(&SB[row * 64 + (((ks * 4 + quad) ^ (c16 & 7)) << 3)]);
    }

  __syncthreads();   // all Q reads complete; SB reusable

  // stage kv tile 0 into buf0 (K at +0, V at +4096 within each 8192-ushort buffer)
  async16(kp, &SB[ldsoff]); async16(vp, &SB[4096 + ldsoff]);
  kp += (size_t)64 * DMODEL; vp += 64;

  float l_i[2] = {0.f, 0.f};
  f32x4 o_acc[2][4];
  f32x4 zero = {0.f, 0.f, 0.f, 0.f};
#pragma unroll
  for (int n = 0; n < 2; ++n)
#pragma unroll
    for (int m = 0; m < 4; ++m) o_acc[n][m] = zero;

  const int niter = (len + 63) >> 6;
  for (int it = 0; it < niter; ++it) {
    __syncthreads();   // publish buf it&1 (drains staging); prior-iter LDS reads done
    const ushort* Kt = &SB[(it & 1) * 8192];
    const ushort* Vt = Kt + 4096;

    // prefetch next kv-tile into the other buffer — overlaps this iteration's compute
    if (it + 1 < niter) {
      ushort* Dst = &SB[((it + 1) & 1) * 8192];
      async16(kp, Dst + ldsoff); async16(vp, Dst + 4096 + ldsoff);
      kp += (size_t)64 * DMODEL; vp += 64;
    }

    // S^T = K * Q^T : A = K-frag (m=kv), B = Q-frag (n=q). C: row(kv)=quad*4+reg, col(q)=c16
    f32x4 s[2][4];
    __builtin_amdgcn_s_setprio(1);
#pragma unroll
    for (int f = 0; f < 4; ++f) {
      const int row = f * 16 + c16;
      const int ch = c16 & 7;
      bf16x8 ak0 = *(const bf16x8*)(Kt + row * 64 + ((quad ^ ch) << 3));
      bf16x8 ak1 = *(const bf16x8*)(Kt + row * 64 + (((4 + quad) ^ ch) << 3));
#pragma unroll
      for (int n = 0; n < 2; ++n) {
        s[n][f] = zero;
        s[n][f] = __builtin_amdgcn_mfma_f32_16x16x32_bf16(ak0, aq[n][0], s[n][f], 0, 0, 0);
        s[n][f] = __builtin_amdgcn_mfma_f32_16x16x32_bf16(ak1, aq[n][1], s[n][f], 0, 0, 0);
      }
    }
    __builtin_amdgcn_s_setprio(0);

    // mask invalid kv (only last iteration; garbage K rows -> masked here)
    const int kv0 = it * 64;
    if (kv0 + 64 > len) {
#pragma unroll
      for (int f = 0; f < 4; ++f) {
        const int kvb = kv0 + f * 16 + quad * 4;
#pragma unroll
        for (int r = 0; r < 4; ++r)
          if (kvb + r >= len) { s[0][f][r] = NEGV; s[1][f][r] = NEGV; }
      }
    }

    // no-max softmax: p = exp2(s) directly (raw v_exp_f32; exp2(-1e30)=0 exactly).
    // 4 independent partial-l chains per n (dep depth 8, was 32 serial adds).
#pragma unroll
    for (int n = 0; n < 2; ++n) {
      float p0 = 0.f, p1 = 0.f, p2 = 0.f, p3 = 0.f;
#pragma unroll
      for (int f = 0; f < 4; ++f) {
        const float e0 = EXP2F(s[n][f][0]);
        const float e1 = EXP2F(s[n][f][1]);
        const float e2 = EXP2F(s[n][f][2]);
        const float e3 = EXP2F(s[n][f][3]);
        s[n][f][0] = e0; s[n][f][1] = e1; s[n][f][2] = e2; s[n][f][3] = e3;
        p0 += e0; p1 += e1; p2 += e2; p3 += e3;
      }
      l_i[n] += (p0 + p1) + (p2 + p3);
    }

    // pack P^T (registers) as B-operand: slot (quad,j) <-> kv = g*32 + (j>>2)*16 + quad*4 + (j&3)
    // compiler casts fuse to v_cvt_pk_bf16_f32 (proven faster than hand bit-packing)
    bf16x8 bp[2][2];
#pragma unroll
    for (int n = 0; n < 2; ++n)
#pragma unroll
      for (int g = 0; g < 2; ++g) {
        bf16x8 t;
#pragma unroll
        for (int r = 0; r < 4; ++r) {
          t[r]     = (__bf16)s[n][2 * g][r];
          t[r + 4] = (__bf16)s[n][2 * g + 1][r];
        }
        bp[n][g] = t;
      }

    // O^T += V^T * P^T : A = V^T-frag (m=d), B = P^T (regs). C: row(d)=quad*4+reg, col(q)=c16
    __builtin_amdgcn_s_setprio(1);
#pragma unroll
    for (int m = 0; m < 4; ++m) {
      const int row = m * 16 + c16;
      const int ch = c16 & 7;
      bf16x8 av0 = *(const bf16x8*)(Vt + row * 64 + ((quad ^ ch) << 3));
      bf16x8 av1 = *(const bf16x8*)(Vt + row * 64 + (((4 + quad) ^ ch) << 3));
#pragma unroll
      for (int n = 0; n < 2; ++n) {
        o_acc[n][m] = __builtin_amdgcn_mfma_f32_16x16x32_bf16(av0, bp[n][0], o_acc[n][m], 0, 0, 0);
        o_acc[n][m] = __builtin_amdgcn_mfma_f32_16x16x32_bf16(av1, bp[n][1], o_acc[n][m], 0, 0, 0);
      }
    }
    __builtin_amdgcn_s_setprio(0);
  }

  // epilogue: reduce l across quads, normalize, store bf16.
  // O^T: d = m*16+quad*4+r, q = wave*32+n*16+c16
#pragma unroll
  for (int n = 0; n < 2; ++n) {
    float l = l_i[n];
    l += __shfl_xor(l, 16);
    l += __shfl_xor(l, 32);
    const int q = q0 + wave * 32 + n * 16 + c16;
    if (q < len) {
      const float inv = 1.0f / l;
      const size_t base = (size_t)(seg0 + q) * DMODEL + h * DHEAD;
#pragma unroll
      for (int m = 0; m < 4; ++m) {
        ushort4 pk;
        pk.x = f2bf(o_acc[n][m][0] * inv);
        pk.y = f2bf(o_acc[n][m][1] * inv);
        pk.z = f2bf(o_acc[n][m][2] * inv);
        pk.w = f2bf(o_acc[n][m][3] * inv);
        *(ushort4*)(ob + base + m * 16 + quad * 4) = pk;
      }
    }
  }
}

// ---------------- launch ----------------
extern "C" void kernel_launch(void* const* d_in, const int* in_sizes, int n_in,
                              void* d_out, int out_size, void* d_ws, size_t ws_size,
                              hipStream_t stream)
{
  (void)n_in; (void)out_size; (void)ws_size;
  const float* hs = (const float*)d_in[0];
  const int*   cu = (const int*)d_in[1];
  const float* Wq = (const float*)d_in[2];
  const float* bq = (const float*)d_in[3];
  const float* Wk = (const float*)d_in[4];
  const float* Wv = (const float*)d_in[5];
  const float* bv = (const float*)d_in[6];
  const float* Wo = (const float*)d_in[7];
  const float* bo = (const float*)d_in[8];
  float* out = (float*)d_out;
  const int T  = in_sizes[0] / DMODEL;            // 6000
  const int DD = DMODEL * DMODEL;
  const int nX = T * DMODEL;

  // workspace layout (ushort elements):
  //   [0]      X bf16 [T,D]   (reused as ob after gemm_qkv)
  //   [nX]     W4 bf16 [4][D,D]
  //   [+4DD]   qb [T,D]
  //   [+T*D]   kb [T,D]
  //   [+T*D]   vt [D][NSEG][SPAD]   (last region: attn OOB row reads stay inside ws)
  ushort* ws  = (ushort*)d_ws;
  ushort* X   = ws;
  ushort* W4  = X + (size_t)nX;
  ushort* qb  = W4 + 4 * (size_t)DD;
  ushort* kb  = qb + (size_t)T * DMODEL;
  ushort* vt  = kb + (size_t)T * DMODEL;
  ushort* ob  = X;                                // X dead after gemm_qkv

  cvt_all<<<2048, 256, 0, stream>>>(hs, Wq, Wk, Wv, Wo, ws, nX, DD);

  gemm_qkv<<<dim3(32, (T + BM - 1) / BM), 256, 0, stream>>>(
      X, W4, bq, bv, cu, qb, kb, vt, T);

  attn_fused<<<dim3(NSEG * NHEAD, QT256), 512, 0, stream>>>(qb, kb, vt, ob, cu, T);

  gemm_out<<<dim3(10, (T + OBM - 1) / OBM), 128, 0, stream>>>(
      ob, W4 + 3 * (size_t)DD, bo, out, T);
}

// Round 11
// 295.252 us; speedup vs baseline: 1.8055x; 1.0115x over previous
//
#include <hip/hip_runtime.h>
#include <stdint.h>
#include <math.h>

#define DMODEL 1280
#define NHEAD  20
#define DHEAD  64
#define NSEG   4
#define MAXS   1500
#define SPAD   1536              // padded per-segment kv length (multiple of 64)
#define TPAD   (NSEG*SPAD)       // 6144
#define QT256  ((MAXS + 255) / 256)  // 6 q-tiles for attention (256 q-rows/block)
#define BM 128
#define BN 128
#define BK 32
#define OBM 64                   // gemm_out tile (2-wave blocks)
#define OBN 128
#define QSCALE 0.18033688011112042f  // 0.125 * log2(e): fold softmax scale+log2e into Q
#define NEGV  -1e30f

typedef float  f32x4  __attribute__((ext_vector_type(4)));
typedef __bf16 bf16x8 __attribute__((ext_vector_type(8)));

#if __has_builtin(__builtin_amdgcn_exp2f)
#define EXP2F(x) __builtin_amdgcn_exp2f(x)
#else
#define EXP2F(x) exp2f(x)
#endif

__device__ __forceinline__ ushort f2bf(float f) {
  union { float f; uint32_t u; } a; a.f = f;
  uint32_t u = a.u;
  u += 0x7FFFu + ((u >> 16) & 1u);   // RNE
  return (ushort)(u >> 16);
}

// async global->LDS, 16B per lane: lane i lands at lds + i*16 (wave-uniform base).
__device__ __forceinline__ void async16(const void* g, void* lds) {
  __builtin_amdgcn_global_load_lds((const __attribute__((address_space(1))) void*)g,
                                   (__attribute__((address_space(3))) void*)lds,
                                   16, 0, 0);
}

// kv permutation within each 32-block of the transposed-V layout:
// stored position p <-> actual offset a, p = ((a>>2)&3)*8 + ((a>>4)&1)*4 + (a&3)
__device__ __forceinline__ int perm32(int a) {
  return ((a >> 2) & 3) * 8 + ((a >> 4) & 1) * 4 + (a & 3);
}

// ---------------- fused fp32 -> bf16 convert (grid-stride, 32B/thread) --------
// R7 proved this pre-pass earns its ~25 us: fusing fp32 loads into the GEMM doubled
// the cache-side byte footprint (FETCH 70->171 MB) and cost +88 us.
__global__ void __launch_bounds__(256)
cvt_all(const float* __restrict__ hs, const float* __restrict__ Wq,
        const float* __restrict__ Wk, const float* __restrict__ Wv,
        const float* __restrict__ Wo, ushort* __restrict__ dst, int nX, int DD) {
  const int ng = (nX + 4 * DD) >> 3;
  const int stride = gridDim.x * 256;
  for (int g = blockIdx.x * 256 + threadIdx.x; g < ng; g += stride) {
    const int i = g << 3;
    const float* src;
    if (i < nX) {
      src = hs + i;
    } else {
      const int j = i - nX;
      const int z = (j >= DD) + (j >= 2 * DD) + (j >= 3 * DD);
      const float* w = (z == 0) ? Wq : (z == 1) ? Wk : (z == 2) ? Wv : Wo;
      src = w + (j - z * DD);
    }
    const float4 v0 = ((const float4*)src)[0];
    const float4 v1 = ((const float4*)src)[1];
    ushort4 o0, o1;
    o0.x = f2bf(v0.x); o0.y = f2bf(v0.y); o0.z = f2bf(v0.z); o0.w = f2bf(v0.w);
    o1.x = f2bf(v1.x); o1.y = f2bf(v1.y); o1.z = f2bf(v1.z); o1.w = f2bf(v1.w);
    ((ushort4*)(dst + i))[0] = o0;
    ((ushort4*)(dst + i))[1] = o1;
  }
}

// ---------------- GEMM mainloop (C = A[M,K] * W[N,K]^T) ----------------
// Proven structure (measured 5x at ~102-104 us in gemm_qkv): 128x128 tile, 2-buffer
// global_load_lds, ~2.3 blocks/CU. LDS tile: 64 super-rows (2 K-rows) x 8 chunks of
// 16B, chunk pos p' = p ^ (sr&7); 128B super-rows + 3-bit XOR measured 0 bank conflicts.
// NOTE: 9 schedule-structure variants (counted vmcnt, depth-2 3-buf, BK=64/256^2 tile,
// per-z split, fp32-fused staging, coop mega-kernel) all measured null-to-regression
// against this baseline — do not re-attempt without the full 8-phase choreography.
__device__ __forceinline__ void gemm_tile_mainloop(
    const ushort* __restrict__ A, const ushort* __restrict__ W,
    int M, int m0, int n0, ushort* As, ushort* Bs, f32x4 (&acc)[4][4])
{
  const int tid  = threadIdx.x;
  const int wave = tid >> 6, lane = tid & 63;
  const int quad = lane >> 4, c16 = lane & 15;
  const int wr = (wave >> 1) * 64, wc = (wave & 1) * 64;

  const int M0 = wave * 128 + lane, M1 = M0 + 64;
  const int sr0 = M0 >> 3, pp0 = M0 & 7, p0 = pp0 ^ (sr0 & 7);
  const int sr1 = M1 >> 3, pp1 = M1 & 7, p1 = pp1 ^ (sr1 & 7);
  const int row0 = sr0 * 2 + (p0 >> 2), kc0 = (p0 & 3) << 3;
  const int row1 = sr1 * 2 + (p1 >> 2), kc1 = (p1 & 3) << 3;
  // no row clamp: OOB rows (m-edge tile) read into the next ws region; results masked at store
  const ushort* Ap0 = A + (size_t)(m0 + row0) * DMODEL + kc0;
  const ushort* Ap1 = A + (size_t)(m0 + row1) * DMODEL + kc1;
  const ushort* Bp0 = W + (size_t)(n0 + row0) * DMODEL + kc0;
  const ushort* Bp1 = W + (size_t)(n0 + row1) * DMODEL + kc1;
  const int o0 = wave * 1024;
  const int o1 = wave * 1024 + 512;
  const int BUF = BM * BK;           // 4096 ushorts per buffer

  async16(Ap0, As + o0); async16(Ap1, As + o1);
  async16(Bp0, Bs + o0); async16(Bp1, Bs + o1);

  int c = 0;
  for (int k0 = 0; k0 < DMODEL; k0 += BK, c ^= 1) {
    __syncthreads();                 // publishes buf c (drains the staging loads)
    if (k0 + BK < DMODEL) {
      const int kn = k0 + BK;
      const int bo = (c ^ 1) * BUF;
      async16(Ap0 + kn, As + bo + o0); async16(Ap1 + kn, As + bo + o1);
      async16(Bp0 + kn, Bs + bo + o0); async16(Bp1 + kn, Bs + bo + o1);
    }
    const ushort* Ab = As + c * BUF;
    const ushort* Bb = Bs + c * BUF;
    bf16x8 a[4], b[4];
#pragma unroll
    for (int i = 0; i < 4; ++i) {
      const int row = wr + i * 16 + c16;
      const int sr = row >> 1;
      const int off = (sr << 6) + (((((row & 1) << 2) | quad) ^ (sr & 7)) << 3);
      a[i] = *(const bf16x8*)(Ab + off);
    }
#pragma unroll
    for (int j = 0; j < 4; ++j) {
      const int row = wc + j * 16 + c16;
      const int sr = row >> 1;
      const int off = (sr << 6) + (((((row & 1) << 2) | quad) ^ (sr & 7)) << 3);
      b[j] = *(const bf16x8*)(Bb + off);
    }
#pragma unroll
    for (int i = 0; i < 4; ++i)
#pragma unroll
      for (int j = 0; j < 4; ++j)
        acc[i][j] = __builtin_amdgcn_mfma_f32_16x16x32_bf16(a[i], b[j], acc[i][j], 0, 0, 0);
  }
}

// ---------------- fused QKV projection, bf16 out (Q pre-scaled, V written transposed) ----
// grid (32, 47): x = weight-group (z*10 + ntile). gridDim.x=32 keeps linear block id
// = y*32+x, so XCD = x%8 is y-invariant: all 47 m-tiles of one (z,n) group pin to one
// XCD and its W-panel (3.3 MB) stays resident in that XCD's 4 MB L2. FUSED (not per-z
// split): R4 attribution showed splitting costs ~+20 us (loses X-panel L2 sharing).
__global__ void __launch_bounds__(256, 4)
gemm_qkv(const ushort* __restrict__ X, const ushort* __restrict__ W4,
         const float* __restrict__ bq, const float* __restrict__ bv,
         const int* __restrict__ cu,
         ushort* __restrict__ qb, ushort* __restrict__ kb, ushort* __restrict__ vt, int M)
{
  __shared__ ushort As[2 * BM * BK], Bs[2 * BN * BK];
  const int wg = blockIdx.x;
  if (wg >= 30) return;
  const int z = wg / 10;
  const int n0 = (wg % 10) * BN;
  const int m0 = blockIdx.y * BM;
  const ushort* W = W4 + (size_t)z * DMODEL * DMODEL;

  f32x4 acc[4][4];
  f32x4 zero = {0.f, 0.f, 0.f, 0.f};
#pragma unroll
  for (int i = 0; i < 4; ++i)
#pragma unroll
    for (int j = 0; j < 4; ++j) acc[i][j] = zero;

  gemm_tile_mainloop(X, W, M, m0, n0, As, Bs, acc);

  const int tid = threadIdx.x, wave = tid >> 6, lane = tid & 63;
  const int quad = lane >> 4, c16 = lane & 15;
  const int wr = (wave >> 1) * 64, wc = (wave & 1) * 64;

  if (z == 2) {
    // V: write directly into transposed + kv-permuted layout vt[D][NSEG][SPAD]
    const int c1 = cu[1], c2 = cu[2], c3 = cu[3];
#pragma unroll
    for (int i = 0; i < 4; ++i) {
      const int t0 = m0 + wr + i * 16 + quad * 4;
      const int s0a = (t0 >= c1) + (t0 >= c2) + (t0 >= c3);
      const int s3a = (t0 + 3 >= c1) + (t0 + 3 >= c2) + (t0 + 3 >= c3);
      const int seg0 = (s0a == 0) ? 0 : (s0a == 1) ? c1 : (s0a == 2) ? c2 : c3;
#pragma unroll
      for (int j = 0; j < 4; ++j) {
        const int cfeat = n0 + wc + j * 16 + c16;
        const float bb = bv[cfeat];
        if (t0 + 3 < M && s0a == s3a) {
          const int s = t0 - seg0;                 // s ≡ t0 (mod 4): boundaries are mult of 4
          const size_t base = (size_t)cfeat * TPAD + (size_t)s0a * SPAD
                            + (size_t)(s & ~31) + perm32(s & 31);
          ushort4 w;
          w.x = f2bf(acc[i][j][0] + bb);
          w.y = f2bf(acc[i][j][1] + bb);
          w.z = f2bf(acc[i][j][2] + bb);
          w.w = f2bf(acc[i][j][3] + bb);
          *(ushort4*)(vt + base) = w;
        } else {
#pragma unroll
          for (int r = 0; r < 4; ++r) {
            const int t = t0 + r;
            if (t < M) {
              const int sb = (t >= c1) + (t >= c2) + (t >= c3);
              const int sg = (sb == 0) ? 0 : (sb == 1) ? c1 : (sb == 2) ? c2 : c3;
              const int s = t - sg;
              vt[(size_t)cfeat * TPAD + (size_t)sb * SPAD + (s & ~31) + perm32(s & 31)]
                  = f2bf(acc[i][j][r] + bb);
            }
          }
        }
      }
    }
  } else {
    ushort* out = (z == 0) ? qb : kb;
    const float* bias = (z == 0) ? bq : (const float*)nullptr;
    const float oscale = (z == 0) ? QSCALE : 1.0f;
#pragma unroll
    for (int i = 0; i < 4; ++i) {
      const int rbase = m0 + wr + i * 16 + quad * 4;
#pragma unroll
      for (int j = 0; j < 4; ++j) {
        const int c = n0 + wc + j * 16 + c16;
        const float bb = bias ? bias[c] : 0.f;
#pragma unroll
        for (int r = 0; r < 4; ++r) {
          const int rr = rbase + r;
          if (rr < M) out[(size_t)rr * DMODEL + c] = f2bf((acc[i][j][r] + bb) * oscale);
        }
      }
    }
  }
}

// ---------------- output projection, fp32 out: 64x128 tile, 2-wave blocks ----------------
// grid (10, 94) = 940 blocks x 128 thr, 24 KB LDS. Per-wave K-step work identical to
// gemm_tile_mainloop (4 A-frag + 4 B-frag + 16 MFMA, same XOR layout, 2-buffer schedule).
__global__ void __launch_bounds__(128, 3)
gemm_out(const ushort* __restrict__ A, const ushort* __restrict__ W,
         const float* __restrict__ bias, float* __restrict__ out, int M)
{
  __shared__ __align__(16) ushort As[2 * OBM * BK], Bs[2 * OBN * BK];   // 8 KB + 16 KB
  const int n0 = blockIdx.x * OBN;
  const int m0 = blockIdx.y * OBM;
  const int tid = threadIdx.x, wave = tid >> 6, lane = tid & 63;
  const int quad = lane >> 4, c16 = lane & 15;

  int rA[2], kA[2], rB[4], kB[4];
#pragma unroll
  for (int q = 0; q < 2; ++q) {
    const int s = tid + q * 128;
    const int sr = s >> 3, p = (s & 7) ^ (sr & 7);
    rA[q] = sr * 2 + (p >> 2); kA[q] = (p & 3) << 3;
  }
#pragma unroll
  for (int q = 0; q < 4; ++q) {
    const int s = tid + q * 128;
    const int sr = s >> 3, p = (s & 7) ^ (sr & 7);
    rB[q] = sr * 2 + (p >> 2); kB[q] = (p & 3) << 3;
  }
  // OOB m-edge rows read into the next ws region; masked at store
  const ushort* ApS0 = A + (size_t)(m0 + rA[0]) * DMODEL + kA[0];
  const ushort* ApS1 = A + (size_t)(m0 + rA[1]) * DMODEL + kA[1];
  const ushort* BpS0 = W + (size_t)(n0 + rB[0]) * DMODEL + kB[0];
  const ushort* BpS1 = W + (size_t)(n0 + rB[1]) * DMODEL + kB[1];
  const ushort* BpS2 = W + (size_t)(n0 + rB[2]) * DMODEL + kB[2];
  const ushort* BpS3 = W + (size_t)(n0 + rB[3]) * DMODEL + kB[3];
  const int aO0 = (wave * 64) * 8,       aO1 = (128 + wave * 64) * 8;
  const int bO0 = (wave * 64) * 8,       bO1 = (128 + wave * 64) * 8;
  const int bO2 = (256 + wave * 64) * 8, bO3 = (384 + wave * 64) * 8;
  const int BUFA = OBM * BK;   // 2048 ushorts
  const int BUFB = OBN * BK;   // 4096 ushorts

#define OSTAGE(c, kk) do { \
    ushort* Ad = As + (c) * BUFA; ushort* Bd = Bs + (c) * BUFB; \
    async16(ApS0 + (kk), Ad + aO0); async16(ApS1 + (kk), Ad + aO1); \
    async16(BpS0 + (kk), Bd + bO0); async16(BpS1 + (kk), Bd + bO1); \
    async16(BpS2 + (kk), Bd + bO2); async16(BpS3 + (kk), Bd + bO3); \
  } while (0)

  f32x4 acc[4][4];
  f32x4 zero = {0.f, 0.f, 0.f, 0.f};
#pragma unroll
  for (int i = 0; i < 4; ++i)
#pragma unroll
    for (int j = 0; j < 4; ++j) acc[i][j] = zero;

  OSTAGE(0, 0);
  int c = 0;
  for (int k0 = 0; k0 < DMODEL; k0 += BK, c ^= 1) {
    __syncthreads();                 // publishes buf c
    if (k0 + BK < DMODEL) OSTAGE(c ^ 1, k0 + BK);
    const ushort* Ab = As + c * BUFA;
    const ushort* Bb = Bs + c * BUFB;
    bf16x8 a[4], b[4];
#pragma unroll
    for (int i = 0; i < 4; ++i) {            // A rows 0..63 (shared by both waves)
      const int row = i * 16 + c16;
      const int sr = row >> 1;
      const int off = (sr << 6) + (((((row & 1) << 2) | quad) ^ (sr & 7)) << 3);
      a[i] = *(const bf16x8*)(Ab + off);
    }
#pragma unroll
    for (int j = 0; j < 4; ++j) {            // B rows wave*64 .. wave*64+63
      const int row = wave * 64 + j * 16 + c16;
      const int sr = row >> 1;
      const int off = (sr << 6) + (((((row & 1) << 2) | quad) ^ (sr & 7)) << 3);
      b[j] = *(const bf16x8*)(Bb + off);
    }
#pragma unroll
    for (int i = 0; i < 4; ++i)
#pragma unroll
      for (int j = 0; j < 4; ++j)
        acc[i][j] = __builtin_amdgcn_mfma_f32_16x16x32_bf16(a[i], b[j], acc[i][j], 0, 0, 0);
  }
#undef OSTAGE

#pragma unroll
  for (int i = 0; i < 4; ++i) {
    const int rbase = m0 + i * 16 + quad * 4;
#pragma unroll
    for (int j = 0; j < 4; ++j) {
      const int cc = n0 + wave * 64 + j * 16 + c16;
      const float bb = bias[cc];
#pragma unroll
      for (int r = 0; r < 4; ++r) {
        const int rr = rbase + r;
        if (rr < M) out[(size_t)rr * DMODEL + cc] = acc[i][j][r] + bb;
      }
    }
  }
}

// ---------------- fused flash attention (8-wave, 256 q-rows/block; measured ~58.5 us) ----
// S^T trick (P stays in registers), no-max softmax, K/V double-buffer in LDS.
// P->bf16 via compiler casts (fuse to v_cvt_pk_bf16_f32) — proven faster than manual
// bit-packing. R9's counted-vmcnt triple-buffer and R10's dep-chain split: both null
// (15 waves/CU of TLP already hides prefetch latency and add-chain latency).
// LDS = 32 KB total: Q staged in all of it, then recycled as KV dbuf [2][8192 ushorts].
// grid: (NSEG*NHEAD, QT256): x = head-seg (pins all q-tiles of one (b,h) to one XCD)
__global__ void __launch_bounds__(512, 4)
attn_fused(const ushort* __restrict__ qb, const ushort* __restrict__ kb,
           const ushort* __restrict__ vt, ushort* __restrict__ ob,
           const int* __restrict__ cu, int T)
{
  __shared__ ushort SB[16384];     // 32 KB
  const int hs = blockIdx.x;
  const int b = hs / NHEAD, h = hs % NHEAD;
  const int seg0 = cu[b];
  const int len  = cu[b + 1] - seg0;
  const int q0 = blockIdx.y * 256;
  if (q0 >= len) return;
  const int tid = threadIdx.x, wave = tid >> 6, lane = tid & 63;
  const int quad = lane >> 4, c16 = lane & 15;

  // ---- stage Q (256 rows x 64 d = 32KB) into SB, pre-swizzled-global chunks ----
#pragma unroll
  for (int t = 0; t < 4; ++t) {
    const int slot = t * 512 + tid;
    const int r = slot >> 3, k2 = slot & 7;
    const int col = ((k2 ^ (r & 7)) << 3);
    async16(qb + (size_t)(seg0 + q0 + r) * DMODEL + h * DHEAD + col,
            &SB[(t * 512 + wave * 64) * 8]);
  }

  // ---- per-lane K/V staging pointers (512 threads cover 64 rows x 8 chunks) ----
  const int rK = tid >> 3, kK = tid & 7;
  const int colK = ((kK ^ (rK & 7)) << 3);
  const ushort* kp = kb + (size_t)(seg0 + rK) * DMODEL + h * DHEAD + colK;
  const ushort* vp = vt + (size_t)(h * DHEAD + rK) * TPAD + (size_t)b * SPAD + colK;
  const int ldsoff = wave * 512;   // ushort offset of this wave's 64 staging slots

  __syncthreads();   // Q published (drains vmcnt)

  // Q fragments -> registers; SB is dead afterwards (recycled as kv double-buffer)
  bf16x8 aq[2][2];
#pragma unroll
  for (int n = 0; n < 2; ++n)
#pragma unroll
    for (int ks = 0; ks < 2; ++ks) {
      const int row = wave * 32 + n * 16 + c16;
      aq[n][ks] = *(const bf16x8*)(&SB[row * 64 + (((ks * 4 + quad) ^ (c16 & 7)) << 3)]);
    }

  __syncthreads();   // all Q reads complete; SB reusable

  // stage kv tile 0 into buf0 (K at +0, V at +4096 within each 8192-ushort buffer)
  async16(kp, &SB[ldsoff]); async16(vp, &SB[4096 + ldsoff]);
  kp += (size_t)64 * DMODEL; vp += 64;

  float l_i[2] = {0.f, 0.f};
  f32x4 o_acc[2][4];
  f32x4 zero = {0.f, 0.f, 0.f, 0.f};
#pragma unroll
  for (int n = 0; n < 2; ++n)
#pragma unroll
    for (int m = 0; m < 4; ++m) o_acc[n][m] = zero;

  const int niter = (len + 63) >> 6;
  for (int it = 0; it < niter; ++it) {
    __syncthreads();   // publish buf it&1 (drains staging); prior-iter LDS reads done
    const ushort* Kt = &SB[(it & 1) * 8192];
    const ushort* Vt = Kt + 4096;

    // prefetch next kv-tile into the other buffer — overlaps this iteration's compute
    if (it + 1 < niter) {
      ushort* Dst = &SB[((it + 1) & 1) * 8192];
      async16(kp, Dst + ldsoff); async16(vp, Dst + 4096 + ldsoff);
      kp += (size_t)64 * DMODEL; vp += 64;
    }

    // S^T = K * Q^T : A = K-frag (m=kv), B = Q-frag (n=q). C: row(kv)=quad*4+reg, col(q)=c16
    f32x4 s[2][4];
    __builtin_amdgcn_s_setprio(1);
#pragma unroll
    for (int f = 0; f < 4; ++f) {
      const int row = f * 16 + c16;
      const int ch = c16 & 7;
      bf16x8 ak0 = *(const bf16x8*)(Kt + row * 64 + ((quad ^ ch) << 3));
      bf16x8 ak1 = *(const bf16x8*)(Kt + row * 64 + (((4 + quad) ^ ch) << 3));
#pragma unroll
      for (int n = 0; n < 2; ++n) {
        s[n][f] = zero;
        s[n][f] = __builtin_amdgcn_mfma_f32_16x16x32_bf16(ak0, aq[n][0], s[n][f], 0, 0, 0);
        s[n][f] = __builtin_amdgcn_mfma_f32_16x16x32_bf16(ak1, aq[n][1], s[n][f], 0, 0, 0);
      }
    }
    __builtin_amdgcn_s_setprio(0);

    // mask invalid kv (only last iteration; garbage K rows -> masked here)
    const int kv0 = it * 64;
    if (kv0 + 64 > len) {
#pragma unroll
      for (int f = 0; f < 4; ++f) {
        const int kvb = kv0 + f * 16 + quad * 4;
#pragma unroll
        for (int r = 0; r < 4; ++r)
          if (kvb + r >= len) { s[0][f][r] = NEGV; s[1][f][r] = NEGV; }
      }
    }

    // no-max softmax: p = exp2(s) directly (raw v_exp_f32; exp2(-1e30)=0 exactly);
    // per-lane partial l, cross-quad reduction deferred to epilogue
#pragma unroll
    for (int n = 0; n < 2; ++n) {
      float rs = 0.f;
#pragma unroll
      for (int f = 0; f < 4; ++f)
#pragma unroll
        for (int r = 0; r < 4; ++r) {
          const float p = EXP2F(s[n][f][r]);
          s[n][f][r] = p;
          rs += p;
        }
      l_i[n] += rs;
    }

    // pack P^T (registers) as B-operand: slot (quad,j) <-> kv = g*32 + (j>>2)*16 + quad*4 + (j&3)
    // compiler casts fuse to v_cvt_pk_bf16_f32 (proven faster than hand bit-packing)
    bf16x8 bp[2][2];
#pragma unroll
    for (int n = 0; n < 2; ++n)
#pragma unroll
      for (int g = 0; g < 2; ++g) {
        bf16x8 t;
#pragma unroll
        for (int r = 0; r < 4; ++r) {
          t[r]     = (__bf16)s[n][2 * g][r];
          t[r + 4] = (__bf16)s[n][2 * g + 1][r];
        }
        bp[n][g] = t;
      }

    // O^T += V^T * P^T : A = V^T-frag (m=d), B = P^T (regs). C: row(d)=quad*4+reg, col(q)=c16
    __builtin_amdgcn_s_setprio(1);
#pragma unroll
    for (int m = 0; m < 4; ++m) {
      const int row = m * 16 + c16;
      const int ch = c16 & 7;
      bf16x8 av0 = *(const bf16x8*)(Vt + row * 64 + ((quad ^ ch) << 3));
      bf16x8 av1 = *(const bf16x8*)(Vt + row * 64 + (((4 + quad) ^ ch) << 3));
#pragma unroll
      for (int n = 0; n < 2; ++n) {
        o_acc[n][m] = __builtin_amdgcn_mfma_f32_16x16x32_bf16(av0, bp[n][0], o_acc[n][m], 0, 0, 0);
        o_acc[n][m] = __builtin_amdgcn_mfma_f32_16x16x32_bf16(av1, bp[n][1], o_acc[n][m], 0, 0, 0);
      }
    }
    __builtin_amdgcn_s_setprio(0);
  }

  // epilogue: reduce l across quads, normalize, store bf16.
  // O^T: d = m*16+quad*4+r, q = wave*32+n*16+c16
#pragma unroll
  for (int n = 0; n < 2; ++n) {
    float l = l_i[n];
    l += __shfl_xor(l, 16);
    l += __shfl_xor(l, 32);
    const int q = q0 + wave * 32 + n * 16 + c16;
    if (q < len) {
      const float inv = 1.0f / l;
      const size_t base = (size_t)(seg0 + q) * DMODEL + h * DHEAD;
#pragma unroll
      for (int m = 0; m < 4; ++m) {
        ushort4 pk;
        pk.x = f2bf(o_acc[n][m][0] * inv);
        pk.y = f2bf(o_acc[n][m][1] * inv);
        pk.z = f2bf(o_acc[n][m][2] * inv);
        pk.w = f2bf(o_acc[n][m][3] * inv);
        *(ushort4*)(ob + base + m * 16 + quad * 4) = pk;
      }
    }
  }
}

// ---------------- launch ----------------
extern "C" void kernel_launch(void* const* d_in, const int* in_sizes, int n_in,
                              void* d_out, int out_size, void* d_ws, size_t ws_size,
                              hipStream_t stream)
{
  (void)n_in; (void)out_size; (void)ws_size;
  const float* hs = (const float*)d_in[0];
  const int*   cu = (const int*)d_in[1];
  const float* Wq = (const float*)d_in[2];
  const float* bq = (const float*)d_in[3];
  const float* Wk = (const float*)d_in[4];
  const float* Wv = (const float*)d_in[5];
  const float* bv = (const float*)d_in[6];
  const float* Wo = (const float*)d_in[7];
  const float* bo = (const float*)d_in[8];
  float* out = (float*)d_out;
  const int T  = in_sizes[0] / DMODEL;            // 6000
  const int DD = DMODEL * DMODEL;
  const int nX = T * DMODEL;

  // workspace layout (ushort elements):
  //   [0]      X bf16 [T,D]   (reused as ob after gemm_qkv)
  //   [nX]     W4 bf16 [4][D,D]
  //   [+4DD]   qb [T,D]
  //   [+T*D]   kb [T,D]
  //   [+T*D]   vt [D][NSEG][SPAD]   (last region: attn OOB row reads stay inside ws)
  ushort* ws  = (ushort*)d_ws;
  ushort* X   = ws;
  ushort* W4  = X + (size_t)nX;
  ushort* qb  = W4 + 4 * (size_t)DD;
  ushort* kb  = qb + (size_t)T * DMODEL;
  ushort* vt  = kb + (size_t)T * DMODEL;
  ushort* ob  = X;                                // X dead after gemm_qkv

  cvt_all<<<2048, 256, 0, stream>>>(hs, Wq, Wk, Wv, Wo, ws, nX, DD);

  gemm_qkv<<<dim3(32, (T + BM - 1) / BM), 256, 0, stream>>>(
      X, W4, bq, bv, cu, qb, kb, vt, T);

  attn_fused<<<dim3(NSEG * NHEAD, QT256), 512, 0, stream>>>(qb, kb, vt, ob, cu, T);

  gemm_out<<<dim3(10, (T + OBM - 1) / OBM), 128, 0, stream>>>(
      ob, W4 + 3 * (size_t)DD, bo, out, T);
}